// Round 2
// baseline (551.696 us; speedup 1.0000x reference)
//
#include <hip/hip_runtime.h>
#include <hip/hip_bf16.h>
#include <stdint.h>

// MLA fused pipeline, fp32 I/O, bf16 MFMA internals.
// R8: m201-geometry GEMM. R7 counters: 6.29M bank conflicts (= +4cy per
// ds_read_b128: 64B-row layout maps reads to 16 of 32 banks) and MfmaUtil 28%
// with 1 block/CU. This version:
//  - BK=64, 2 tile-buffers per operand (2 x 32KB x 2 = 128KB LDS).
//  - st_16x32 subtiled layout: tile stored [R/16][K/32] x (16x32 bf16 =
//    1024B subtiles), swizzle byte ^= ((byte>>9)&1)<<5 (rows 8-15 of each
//    subtile swap 32B halves). Bank-verified: fragment reads are perfectly
//    balanced (8 words/bank). global_load_lds writes exactly one linear
//    subtile per call; the involution is applied on the per-lane global
//    source (both-sides rule), 64B segments stay coalesced.
//  - 4 phases per K-tile (8,4,8,4 ds_reads; 16 MFMA each):
//    {ds_read | 1 half-stage | barrier | lgkmcnt(0)+sched_barrier |
//     setprio(1) 16xMFMA setprio(0) | barrier}.
//  - Stage schedule leads use by 4-6 phases; vmcnt(8) at phases 2 and 4
//    (never 0 in the loop). Ledger: p1 stages A-k1(t+1), p2 B-k1(t+1),
//    p3 A-k0(t+2), p4 B-k0(t+2); gate@p2 retires A/B-k1(t) (read in p3/p4),
//    gate@p4 retires A/B-k0(t+1) (read in t+1 p1/p2). Tail stages clamp
//    their source tile so counts stay uniform.
//  - Same per-acc K summation order as R7 -> bit-identical results.

typedef __bf16 bf16_t;
typedef __bf16 bf16x8 __attribute__((ext_vector_type(8)));
typedef float f32x4 __attribute__((ext_vector_type(4)));

__device__ __forceinline__ void async_copy16(const void* g, void* l) {
  __builtin_amdgcn_global_load_lds(
      (__attribute__((address_space(1))) void*)(void*)g,
      (__attribute__((address_space(3))) void*)l, 16, 0, 0);
}

// ---------------------------------------------------------------------------
// GEMM: C[M,N](ldc) = A[M,K](lda) @ BT[N,K]^T + bias. bf16 in, OT out.
// 256x256 tile, BK=64 dbuf, 512 threads (8 waves 2Mx4N, 128x64 each).
// M%256==0, N%256==0, K%64==0, K>=128.
// ---------------------------------------------------------------------------
template <typename OT>
__global__ __launch_bounds__(512, 2) void gemm_bt256(
    const bf16_t* __restrict__ A, long lda,
    const bf16_t* __restrict__ BT,
    const float* __restrict__ bias,
    OT* __restrict__ C, long ldc,
    int M, int N, int K)
{
  __shared__ __align__(16) bf16_t As[2][16384];   // [buf][32 subtiles x 512]
  __shared__ __align__(16) bf16_t Bs[2][16384];

  const int tid  = threadIdx.x;
  const int lane = tid & 63;
  const int w    = tid >> 6;
  const int wm   = w >> 2, wn = w & 3;            // wave grid 2 x 4
  const int quad = lane >> 4, r16 = lane & 15;
  const long row0 = (long)blockIdx.y * 256;
  const long col0 = (long)blockIdx.x * 256;
  const int NT = K >> 6;

  const bf16_t* Ab = A + row0 * lda;
  const bf16_t* Bb = BT + col0 * (long)K;

  // ds_read element offset within an op-buffer subtile row (st_16x32 swizzle):
  // logical (r=R*16+r16, k=Kc*32+quad*8..): elem = (R*2+Kc)*512 + r16*32 +
  // (quad*8 ^ (r16&8 ? 16 : 0)).
  const int rdoff = r16 * 32 + ((quad * 8) ^ ((r16 & 8) ? 16 : 0));

  // staging per-lane source pieces: one global_load_lds call fills one
  // 1024B subtile linearly; lane l holds (r_in=l>>2, 16B chunk l&3); the
  // inverse swizzle permutes the SOURCE k-chunk for rows 8-15 (lanes >= 32).
  const int srin = lane >> 2;
  const int sksw = ((lane & 3) * 8) ^ ((lane & 32) ? 16 : 0);

  auto stage = [&](const bf16_t* G, long ld, bf16_t* dstOp, int Kc) {
#pragma unroll
    for (int s = 0; s < 2; s++) {
      const int m = s * 8 + w;                    // subtile-row (16 rows each)
      async_copy16(G + (long)(m * 16 + srin) * ld + Kc * 32 + sksw,
                   dstOp + ((m * 2 + Kc) << 9));
    }
  };

  f32x4 acc[8][4];
#pragma unroll
  for (int i = 0; i < 8; i++)
#pragma unroll
    for (int j = 0; j < 4; j++)
      acc[i][j] = (f32x4){0.f, 0.f, 0.f, 0.f};

  // Prologue (steady-state issue order): A/B-k0(0), A/B-k1(0), A/B-k0(1).
  {
    const long k1 = (long)((1 < NT) ? 1 : NT - 1) << 6;
    stage(Ab, lda, As[0], 0);
    stage(Bb, K,   Bs[0], 0);
    stage(Ab, lda, As[0], 1);
    stage(Bb, K,   Bs[0], 1);
    stage(Ab + k1, lda, As[1], 0);
    stage(Bb + k1, K,   Bs[1], 0);
  }
  // 12 outstanding; retire oldest 4 = A/B-k0(0).
  asm volatile("s_waitcnt vmcnt(8)" ::: "memory");
  __builtin_amdgcn_s_barrier();

  for (int t = 0; t < NT; t++) {
    const bf16_t* a0 = As[t & 1];
    const bf16_t* b0 = Bs[t & 1];
    bf16_t* an = As[(t + 1) & 1];
    bf16_t* bn = Bs[(t + 1) & 1];
    bf16_t* ac = As[t & 1];          // k0 region free after p2's barrier
    bf16_t* bc = Bs[t & 1];
    const long k1 = (long)((t + 1 < NT) ? t + 1 : NT - 1) << 6;
    const long k2 = (long)((t + 2 < NT) ? t + 2 : NT - 1) << 6;

    bf16x8 av[4], bv[4];

    // ---- phase 1: kh=0, mh=0 (8 ds_reads) ----
#pragma unroll
    for (int i = 0; i < 4; i++)
      av[i] = *(const bf16x8*)(a0 + (((wm * 8 + i) * 2 + 0) << 9) + rdoff);
#pragma unroll
    for (int j = 0; j < 4; j++)
      bv[j] = *(const bf16x8*)(b0 + (((wn * 4 + j) * 2 + 0) << 9) + rdoff);
    stage(Ab + k1, lda, an, 1);
    asm volatile("" ::: "memory");
    __builtin_amdgcn_s_barrier();
    asm volatile("s_waitcnt lgkmcnt(0)" ::: "memory");
    __builtin_amdgcn_sched_barrier(0);
    __builtin_amdgcn_s_setprio(1);
#pragma unroll
    for (int i = 0; i < 4; i++)
#pragma unroll
      for (int j = 0; j < 4; j++)
        acc[i][j] = __builtin_amdgcn_mfma_f32_16x16x32_bf16(av[i], bv[j], acc[i][j], 0, 0, 0);
    __builtin_amdgcn_s_setprio(0);
    __builtin_amdgcn_sched_barrier(0);
    asm volatile("" ::: "memory");
    __builtin_amdgcn_s_barrier();

    // ---- phase 2: kh=0, mh=1 (4 ds_reads, bv reused) ----
#pragma unroll
    for (int i = 0; i < 4; i++)
      av[i] = *(const bf16x8*)(a0 + (((wm * 8 + 4 + i) * 2 + 0) << 9) + rdoff);
    stage(Bb + k1, K, bn, 1);
    asm volatile("" ::: "memory");
    __builtin_amdgcn_s_barrier();
    asm volatile("s_waitcnt lgkmcnt(0)" ::: "memory");
    __builtin_amdgcn_sched_barrier(0);
    __builtin_amdgcn_s_setprio(1);
#pragma unroll
    for (int i = 0; i < 4; i++)
#pragma unroll
      for (int j = 0; j < 4; j++)
        acc[4 + i][j] = __builtin_amdgcn_mfma_f32_16x16x32_bf16(av[i], bv[j], acc[4 + i][j], 0, 0, 0);
    __builtin_amdgcn_s_setprio(0);
    // gate: retire A/B-k1(t) (staged at t-1 p1/p2), keep 4 newest stages.
    asm volatile("s_waitcnt vmcnt(8)" ::: "memory");
    __builtin_amdgcn_sched_barrier(0);
    asm volatile("" ::: "memory");
    __builtin_amdgcn_s_barrier();

    // ---- phase 3: kh=1, mh=0 (8 ds_reads) ----
#pragma unroll
    for (int i = 0; i < 4; i++)
      av[i] = *(const bf16x8*)(a0 + (((wm * 8 + i) * 2 + 1) << 9) + rdoff);
#pragma unroll
    for (int j = 0; j < 4; j++)
      bv[j] = *(const bf16x8*)(b0 + (((wn * 4 + j) * 2 + 1) << 9) + rdoff);
    stage(Ab + k2, lda, ac, 0);
    asm volatile("" ::: "memory");
    __builtin_amdgcn_s_barrier();
    asm volatile("s_waitcnt lgkmcnt(0)" ::: "memory");
    __builtin_amdgcn_sched_barrier(0);
    __builtin_amdgcn_s_setprio(1);
#pragma unroll
    for (int i = 0; i < 4; i++)
#pragma unroll
      for (int j = 0; j < 4; j++)
        acc[i][j] = __builtin_amdgcn_mfma_f32_16x16x32_bf16(av[i], bv[j], acc[i][j], 0, 0, 0);
    __builtin_amdgcn_s_setprio(0);
    __builtin_amdgcn_sched_barrier(0);
    asm volatile("" ::: "memory");
    __builtin_amdgcn_s_barrier();

    // ---- phase 4: kh=1, mh=1 (4 ds_reads, bv reused) ----
#pragma unroll
    for (int i = 0; i < 4; i++)
      av[i] = *(const bf16x8*)(a0 + (((wm * 8 + 4 + i) * 2 + 1) << 9) + rdoff);
    stage(Bb + k2, K, bc, 0);
    asm volatile("" ::: "memory");
    __builtin_amdgcn_s_barrier();
    asm volatile("s_waitcnt lgkmcnt(0)" ::: "memory");
    __builtin_amdgcn_sched_barrier(0);
    __builtin_amdgcn_s_setprio(1);
#pragma unroll
    for (int i = 0; i < 4; i++)
#pragma unroll
      for (int j = 0; j < 4; j++)
        acc[4 + i][j] = __builtin_amdgcn_mfma_f32_16x16x32_bf16(av[i], bv[j], acc[4 + i][j], 0, 0, 0);
    __builtin_amdgcn_s_setprio(0);
    // gate: retire A/B-k0(t+1) (staged at t p... prior tile), keep newest 4.
    asm volatile("s_waitcnt vmcnt(8)" ::: "memory");
    __builtin_amdgcn_sched_barrier(0);
    asm volatile("" ::: "memory");
    __builtin_amdgcn_s_barrier();
  }

  // Drain remaining staged (garbage) loads before LDS reuse / exit.
  asm volatile("s_waitcnt vmcnt(0)" ::: "memory");
  __builtin_amdgcn_s_barrier();

  // Bias into acc (C/D layout: col=lane&15, row=quad*4+reg, m89-verified).
#pragma unroll
  for (int j = 0; j < 4; j++) {
    const float bj = bias[col0 + wn * 64 + j * 16 + r16];
#pragma unroll
    for (int i = 0; i < 8; i++) {
      acc[i][j][0] += bj; acc[i][j][1] += bj;
      acc[i][j][2] += bj; acc[i][j][3] += bj;
    }
  }

  if constexpr (sizeof(OT) == 2) {
    // Repack epilogue through LDS: 8 wave regions [128][64] -> 512B rows.
    bf16_t* wreg = (w < 4) ? &As[w >> 1][(w & 1) * 8192]
                           : &Bs[(w - 4) >> 1][((w - 4) & 1) * 8192];
#pragma unroll
    for (int i = 0; i < 8; i++)
#pragma unroll
      for (int j = 0; j < 4; j++)
#pragma unroll
        for (int r = 0; r < 4; r++)
          wreg[(i * 16 + quad * 4 + r) * 64 + j * 16 + r16] = (bf16_t)acc[i][j][r];
    asm volatile("s_waitcnt lgkmcnt(0)" ::: "memory");
    __builtin_amdgcn_s_barrier();
#pragma unroll
    for (int it = 0; it < 16; it++) {
      const int r = it * 16 + (tid >> 5);
      const int c = (tid & 31) * 8;
      const int ww = ((r >> 7) << 2) + (c >> 6);
      const bf16_t* src = ((ww < 4) ? &As[ww >> 1][(ww & 1) * 8192]
                                    : &Bs[(ww - 4) >> 1][((ww - 4) & 1) * 8192])
                          + (r & 127) * 64 + (c & 63);
      *(bf16x8*)((bf16_t*)C + (row0 + r) * ldc + col0 + c) = *(const bf16x8*)src;
    }
  } else {
    // fp32 output: 16-lane x 4B = 64B segments, no amplification; direct.
#pragma unroll
    for (int j = 0; j < 4; j++) {
      const long col = col0 + wn * 64 + j * 16 + r16;
#pragma unroll
      for (int i = 0; i < 8; i++) {
        const long row = row0 + wm * 128 + i * 16 + quad * 4;
#pragma unroll
        for (int r = 0; r < 4; r++)
          C[(row + r) * ldc + col] = (OT)acc[i][j][r];
      }
    }
  }
}

// ---------------------------------------------------------------------------
// Weight transpose+convert: in fp32 [R][C] -> out bf16 [C][R]. 32x32 tiles,
// block (32,8). out may point into a stacked [N_tot,K] buffer.
// ---------------------------------------------------------------------------
__global__ void transpose_f32_bf16(const float* __restrict__ in, bf16_t* __restrict__ out,
                                   int R, int C)
{
  __shared__ bf16_t tile[32][33];
  const int cb = blockIdx.x * 32, rb = blockIdx.y * 32;
  const int tx = threadIdx.x, ty = threadIdx.y;
#pragma unroll
  for (int i = 0; i < 32; i += 8)
    tile[ty + i][tx] = (bf16_t)in[(size_t)(rb + ty + i) * C + cb + tx];
  __syncthreads();
#pragma unroll
  for (int i = 0; i < 32; i += 8)
    out[(size_t)(cb + ty + i) * R + rb + tx] = tile[tx][ty + i];
}

// ---------------------------------------------------------------------------
// fp32 -> bf16 elementwise convert, 8 elems/thread. n % 8 == 0.
// ---------------------------------------------------------------------------
__global__ void cvt_f32_bf16(const float* __restrict__ in, bf16_t* __restrict__ out, long n)
{
  const long i = ((long)blockIdx.x * blockDim.x + threadIdx.x) * 8;
  if (i >= n) return;
  const float4 a = *(const float4*)(in + i);
  const float4 b = *(const float4*)(in + i + 4);
  bf16x8 o;
  o[0] = (bf16_t)a.x; o[1] = (bf16_t)a.y; o[2] = (bf16_t)a.z; o[3] = (bf16_t)a.w;
  o[4] = (bf16_t)b.x; o[5] = (bf16_t)b.y; o[6] = (bf16_t)b.z; o[7] = (bf16_t)b.w;
  *(bf16x8*)(out + i) = o;
}

// ---------------------------------------------------------------------------
// Concatenate biases for the merged GEMMs. 9216 threads.
// b1[2048]={bc,bckv,bkr} b2[3072]={bcq,bqr} b3[4096]={bck,bv}
// ---------------------------------------------------------------------------
__global__ void concat_bias(const float* bc, const float* bckv, const float* bkr,
                            const float* bcq, const float* bqr,
                            const float* bck, const float* bv,
                            float* b1, float* b2, float* b3)
{
  const int t = blockIdx.x * 256 + threadIdx.x;
  if (t < 2048) {
    b1[t] = (t < 512) ? bc[t] : (t < 1024) ? bckv[t - 512] : bkr[t - 1024];
  } else if (t < 5120) {
    const int u = t - 2048;
    b2[u] = (u < 2048) ? bcq[u] : bqr[u - 2048];
  } else if (t < 9216) {
    const int u = t - 5120;
    b3[u] = (u < 2048) ? bck[u] : bv[u - 2048];
  }
}

// ---------------------------------------------------------------------------
// Fused RoPE + per-token 16x16 head attention over the fused buffers.
// fused1[8192][2048]: cols 1024.. = kr(pre-rope)
// fused2[8192][3072]: cols 0..2047 = q (overwritten with output), 2048.. = qr
// fused3[8192][4096]: cols 0..2047 = k, 2048.. = v
// ---------------------------------------------------------------------------
__global__ __launch_bounds__(256) void attn_rope(
    const bf16_t* __restrict__ f1, bf16_t* f2, const bf16_t* __restrict__ f3)
{
  const int tok = blockIdx.x;
  const int pos = tok & 4095;   // position within sequence (S=4096)
  const int tid = threadIdx.x;

  __shared__ __align__(16) float qf[16 * 204];
  __shared__ __align__(16) float kf[16 * 204];
  __shared__ __align__(16) float vf[16 * 132];
  __shared__ float sc[256];

  const bf16_t* q  = f2 + (size_t)tok * 3072;
  const bf16_t* qr = q + 2048;
  const bf16_t* k  = f3 + (size_t)tok * 4096;
  const bf16_t* v  = k + 2048;
  const bf16_t* kr = f1 + (size_t)tok * 2048 + 1024;

  {
    const int h = tid >> 4, d = (tid & 15) * 8;
    bf16x8 xq = *(const bf16x8*)(q + tid * 8);
    bf16x8 xk = *(const bf16x8*)(k + tid * 8);
    bf16x8 xv = *(const bf16x8*)(v + tid * 8);
    float* qd = qf + h * 204 + d;
    float* kd = kf + h * 204 + d;
    float* vd = vf + h * 132 + d;
#pragma unroll
    for (int e = 0; e < 8; e++) {
      qd[e] = (float)xq[e];
      kd[e] = (float)xk[e];
      vd[e] = (float)xv[e];
    }
  }

  // RoPE: inv_freq[j] = 10000^(-j/32) = 2^(-j*log2(10000)/32)
  for (int p = tid; p < 512; p += 256) {
    const int h = p >> 5, j = p & 31;
    const float x1 = (float)qr[h * 64 + j];
    const float x2 = (float)qr[h * 64 + j + 32];
    const float y1 = (float)kr[h * 64 + j];
    const float y2 = (float)kr[h * 64 + j + 32];
    const float ang = (float)pos * exp2f((float)j * -0.41524101186092029f);
    float sn, cs;
    sincosf(ang, &sn, &cs);
    qf[h * 204 + 128 + j] = x1 * cs - x2 * sn;
    qf[h * 204 + 160 + j] = x2 * cs + x1 * sn;
    kf[h * 204 + 128 + j] = y1 * cs - y2 * sn;
    kf[h * 204 + 160 + j] = y2 * cs + y1 * sn;
  }
  __syncthreads();

  {
    const int i = tid >> 4, j = tid & 15;
    const float4* qrow = (const float4*)(qf + i * 204);
    const float4* krow = (const float4*)(kf + j * 204);
    float d0 = 0.f, d1 = 0.f, d2 = 0.f, d3 = 0.f;
#pragma unroll 8
    for (int dd = 0; dd < 48; dd++) {
      const float4 a = qrow[dd], b = krow[dd];
      d0 = fmaf(a.x, b.x, d0);
      d1 = fmaf(a.y, b.y, d1);
      d2 = fmaf(a.z, b.z, d2);
      d3 = fmaf(a.w, b.w, d3);
    }
    const float s = (d0 + d1 + d2 + d3) * 0.07216878364870323f; // 1/sqrt(192)
    float m = s;
    m = fmaxf(m, __shfl_xor(m, 1));
    m = fmaxf(m, __shfl_xor(m, 2));
    m = fmaxf(m, __shfl_xor(m, 4));
    m = fmaxf(m, __shfl_xor(m, 8));
    const float e = __expf(s - m);
    float sum = e;
    sum += __shfl_xor(sum, 1);
    sum += __shfl_xor(sum, 2);
    sum += __shfl_xor(sum, 4);
    sum += __shfl_xor(sum, 8);
    sc[i * 16 + j] = e / sum;
  }
  __syncthreads();

  {
    const int i = tid >> 4, dp = (tid & 15) * 8;
    float4 a0 = {0.f, 0.f, 0.f, 0.f}, a1 = {0.f, 0.f, 0.f, 0.f};
#pragma unroll
    for (int j = 0; j < 16; j++) {
      const float a = sc[i * 16 + j];
      const float4* vrow = (const float4*)(vf + j * 132 + dp);
      const float4 v0 = vrow[0], v1 = vrow[1];
      a0.x = fmaf(a, v0.x, a0.x);
      a0.y = fmaf(a, v0.y, a0.y);
      a0.z = fmaf(a, v0.z, a0.z);
      a0.w = fmaf(a, v0.w, a0.w);
      a1.x = fmaf(a, v1.x, a1.x);
      a1.y = fmaf(a, v1.y, a1.y);
      a1.z = fmaf(a, v1.z, a1.z);
      a1.w = fmaf(a, v1.w, a1.w);
    }
    bf16x8 o;
    o[0] = (bf16_t)a0.x; o[1] = (bf16_t)a0.y; o[2] = (bf16_t)a0.z; o[3] = (bf16_t)a0.w;
    o[4] = (bf16_t)a1.x; o[5] = (bf16_t)a1.y; o[6] = (bf16_t)a1.z; o[7] = (bf16_t)a1.w;
    // write over q columns of fused2 (this block read its own q above)
    *(bf16x8*)(f2 + (size_t)tok * 3072 + i * 128 + dp) = o;
  }
}

// ---------------------------------------------------------------------------
extern "C" void kernel_launch(void* const* d_in, const int* in_sizes, int n_in,
                              void* d_out, int out_size, void* d_ws, size_t ws_size,
                              hipStream_t stream)
{
  (void)in_sizes; (void)n_in; (void)out_size; (void)ws_size;

  const float* h_t  = (const float*)d_in[0];
  const float* Wc   = (const float*)d_in[1];
  const float* bc   = (const float*)d_in[2];
  const float* Wcq  = (const float*)d_in[3];
  const float* bcq  = (const float*)d_in[4];
  const float* Wqr  = (const float*)d_in[5];
  const float* bqr  = (const float*)d_in[6];
  const float* Wckv = (const float*)d_in[7];
  const float* bckv = (const float*)d_in[8];
  const float* Wck  = (const float*)d_in[9];
  const float* bck  = (const float*)d_in[10];
  const float* Wkr  = (const float*)d_in[11];
  const float* bkr  = (const float*)d_in[12];
  const float* Wv   = (const float*)d_in[13];
  const float* bv   = (const float*)d_in[14];
  const float* Wo   = (const float*)d_in[15];
  const float* bo   = (const float*)d_in[16];

  bf16_t* ws = (bf16_t*)d_ws;
  // ws layout (bf16 elems) — total 87,556,096 = 175,112,192 B (proven fit R4)
  bf16_t* W1T    = ws + 0;         // [2048,2048] rows: WcT 0-511, WckvT 512-1023, WkrT 1024-2047
  bf16_t* W2T    = ws + 4194304;   // [3072,512]  rows: WcqT 0-2047, WqrT 2048-3071
  bf16_t* W3T    = ws + 5767168;   // [4096,512]  rows: WckT 0-2047, WvT 2048-4095
  bf16_t* WoT    = ws + 7864320;   // [2048,2048]
  bf16_t* fused1 = ws + 12058624;  // [8192,2048] cq|ckv|kr_pre
  bf16_t* fused2 = ws + 28835840;  // [8192,3072] q|qr  (q cols become attn out)
  bf16_t* fused3 = ws + 54001664;  // [8192,4096] k|v

  // d_out as scratch until the final GEMM: bf16 h_t copy + concat'd biases
  bf16_t* hbf = (bf16_t*)d_out;                          // 16,777,216 elems (33.5 MB)
  float*  b1  = (float*)((char*)d_out + 33554432);       // 2048 f
  float*  b2  = b1 + 2048;                               // 3072 f
  float*  b3  = b2 + 3072;                               // 4096 f

  const dim3 tb(32, 8);
  transpose_f32_bf16<<<dim3(16, 64), tb, 0, stream>>>(Wc,   W1T,                2048, 512);
  transpose_f32_bf16<<<dim3(16, 64), tb, 0, stream>>>(Wckv, W1T + 512  * 2048,  2048, 512);
  transpose_f32_bf16<<<dim3(32, 64), tb, 0, stream>>>(Wkr,  W1T + 1024 * 2048,  2048, 1024);
  transpose_f32_bf16<<<dim3(64, 16), tb, 0, stream>>>(Wcq,  W2T,                512, 2048);
  transpose_f32_bf16<<<dim3(32, 16), tb, 0, stream>>>(Wqr,  W2T + 2048 * 512,   512, 1024);
  transpose_f32_bf16<<<dim3(64, 16), tb, 0, stream>>>(Wck,  W3T,                512, 2048);
  transpose_f32_bf16<<<dim3(64, 16), tb, 0, stream>>>(Wv,   W3T + 2048 * 512,   512, 2048);
  transpose_f32_bf16<<<dim3(64, 64), tb, 0, stream>>>(Wo,   WoT,                2048, 2048);
  concat_bias<<<36, 256, 0, stream>>>(bc, bckv, bkr, bcq, bqr, bck, bv, b1, b2, b3);
  cvt_f32_bf16<<<8192, 256, 0, stream>>>(h_t, hbf, 16777216L);

  // stage 1: [cq|ckv|kr_pre] = hbf @ [Wc|Wckv|Wkr]   M=8192 N=2048 K=2048
  gemm_bt256<bf16_t><<<dim3(8, 32), 512, 0, stream>>>(hbf, 2048, W1T, b1, fused1, 2048, 8192, 2048, 2048);
  // stage 2a: [q|qr] = cq @ [Wcq|Wqr]                M=8192 N=3072 K=512
  gemm_bt256<bf16_t><<<dim3(12, 32), 512, 0, stream>>>(fused1, 2048, W2T, b2, fused2, 3072, 8192, 3072, 512);
  // stage 2b: [k|v] = ckv @ [Wck|Wv]                 M=8192 N=4096 K=512
  gemm_bt256<bf16_t><<<dim3(16, 32), 512, 0, stream>>>(fused1 + 512, 2048, W3T, b3, fused3, 4096, 8192, 4096, 512);

  // fused rope + attention (output over q cols of fused2)
  attn_rope<<<8192, 256, 0, stream>>>(fused1, fused2, fused3);

  // output projection -> fp32 d_out                  M=8192 N=2048 K=2048
  gemm_bt256<float><<<dim3(8, 32), 512, 0, stream>>>(fused2, 3072, WoT, bo, (float*)d_out, 2048, 8192, 2048, 2048);
}

// Round 3
// 495.148 us; speedup vs baseline: 1.1142x; 1.1142x over previous
//
#include <hip/hip_runtime.h>
#include <hip/hip_bf16.h>
#include <stdint.h>

// MLA fused pipeline, fp32 I/O, bf16 MFMA internals.
// R9: R8 minus the scheduling poison. R8 counters: conflicts 6.29M -> 0
// (st_16x32 swizzle verified) but dur 100->115us, MfmaUtil 23%: the inline
// lgkmcnt(0) + sched_barrier(0) walls serialized LDS drain vs MFMA per phase
// (m141 failure mode: order-pinning defeats compiler fine-grained lgkmcnt).
// This version keeps: BK=64 dbuf, 4 phases/K-tile (8,4,8,4 ds_reads; 16 MFMA
// each), counted vmcnt(8) gates at p2/p4 (never 0 in loop), setprio around
// MFMA, 2 raw barriers per phase, st_16x32 swizzled LDS staged by
// global_load_lds with inverse-swizzled global source.
// Removed: all sched_barrier(0), all in-loop hard lgkmcnt(0). Compiler now
// emits fine-grained lgkmcnt before each dependent MFMA -> ds_read stream
// overlaps the MFMA cluster. Compiler fences only where correctness needs:
// before each stage issue (read-before-overwrite) and after gate barriers
// (no read hoist above the staged-data rendezvous). Same per-acc K summation
// order -> bit-identical results.

typedef __bf16 bf16_t;
typedef __bf16 bf16x8 __attribute__((ext_vector_type(8)));
typedef float f32x4 __attribute__((ext_vector_type(4)));

__device__ __forceinline__ void async_copy16(const void* g, void* l) {
  __builtin_amdgcn_global_load_lds(
      (__attribute__((address_space(1))) void*)(void*)g,
      (__attribute__((address_space(3))) void*)l, 16, 0, 0);
}

// ---------------------------------------------------------------------------
// GEMM: C[M,N](ldc) = A[M,K](lda) @ BT[N,K]^T + bias. bf16 in, OT out.
// 256x256 tile, BK=64 dbuf, 512 threads (8 waves 2Mx4N, 128x64 each).
// M%256==0, N%256==0, K%64==0, K>=128.
// ---------------------------------------------------------------------------
template <typename OT>
__global__ __launch_bounds__(512, 2) void gemm_bt256(
    const bf16_t* __restrict__ A, long lda,
    const bf16_t* __restrict__ BT,
    const float* __restrict__ bias,
    OT* __restrict__ C, long ldc,
    int M, int N, int K)
{
  __shared__ __align__(16) bf16_t As[2][16384];   // [buf][32 subtiles x 512]
  __shared__ __align__(16) bf16_t Bs[2][16384];

  const int tid  = threadIdx.x;
  const int lane = tid & 63;
  const int w    = tid >> 6;
  const int wm   = w >> 2, wn = w & 3;            // wave grid 2 x 4
  const int quad = lane >> 4, r16 = lane & 15;
  const long row0 = (long)blockIdx.y * 256;
  const long col0 = (long)blockIdx.x * 256;
  const int NT = K >> 6;

  const bf16_t* Ab = A + row0 * lda;
  const bf16_t* Bb = BT + col0 * (long)K;

  // ds_read element offset within an op-buffer subtile row (st_16x32 swizzle):
  // logical (r=R*16+r16, k=Kc*32+quad*8..): elem = (R*2+Kc)*512 + r16*32 +
  // (quad*8 ^ (r16&8 ? 16 : 0)).
  const int rdoff = r16 * 32 + ((quad * 8) ^ ((r16 & 8) ? 16 : 0));

  // staging per-lane source pieces: one global_load_lds call fills one
  // 1024B subtile linearly; lane l holds (r_in=l>>2, 16B chunk l&3); the
  // inverse swizzle permutes the SOURCE k-chunk for rows 8-15 (lanes >= 32).
  const int srin = lane >> 2;
  const int sksw = ((lane & 3) * 8) ^ ((lane & 32) ? 16 : 0);

  auto stage = [&](const bf16_t* G, long ld, bf16_t* dstOp, int Kc) {
#pragma unroll
    for (int s = 0; s < 2; s++) {
      const int m = s * 8 + w;                    // subtile-row (16 rows each)
      async_copy16(G + (long)(m * 16 + srin) * ld + Kc * 32 + sksw,
                   dstOp + ((m * 2 + Kc) << 9));
    }
  };

  f32x4 acc[8][4];
#pragma unroll
  for (int i = 0; i < 8; i++)
#pragma unroll
    for (int j = 0; j < 4; j++)
      acc[i][j] = (f32x4){0.f, 0.f, 0.f, 0.f};

  // Prologue (steady-state issue order): A/B-k0(0), A/B-k1(0), A/B-k0(1).
  {
    const long k1 = (long)((1 < NT) ? 1 : NT - 1) << 6;
    stage(Ab, lda, As[0], 0);
    stage(Bb, K,   Bs[0], 0);
    stage(Ab, lda, As[0], 1);
    stage(Bb, K,   Bs[0], 1);
    stage(Ab + k1, lda, As[1], 0);
    stage(Bb + k1, K,   Bs[1], 0);
  }
  // 12 outstanding; retire oldest 4 = A/B-k0(0).
  asm volatile("s_waitcnt vmcnt(8)" ::: "memory");
  __builtin_amdgcn_s_barrier();
  asm volatile("" ::: "memory");

  for (int t = 0; t < NT; t++) {
    const bf16_t* a0 = As[t & 1];
    const bf16_t* b0 = Bs[t & 1];
    bf16_t* an = As[(t + 1) & 1];
    bf16_t* bn = Bs[(t + 1) & 1];
    bf16_t* ac = As[t & 1];          // k0 region free after p2's barrier
    bf16_t* bc = Bs[t & 1];
    const long k1 = (long)((t + 1 < NT) ? t + 1 : NT - 1) << 6;
    const long k2 = (long)((t + 2 < NT) ? t + 2 : NT - 1) << 6;

    bf16x8 av[4], bv[4];

    // ---- phase 1: kh=0, mh=0 (8 ds_reads) ----
#pragma unroll
    for (int i = 0; i < 4; i++)
      av[i] = *(const bf16x8*)(a0 + (((wm * 8 + i) * 2 + 0) << 9) + rdoff);
#pragma unroll
    for (int j = 0; j < 4; j++)
      bv[j] = *(const bf16x8*)(b0 + (((wn * 4 + j) * 2 + 0) << 9) + rdoff);
    asm volatile("" ::: "memory");
    stage(Ab + k1, lda, an, 1);
    __builtin_amdgcn_s_barrier();
    __builtin_amdgcn_s_setprio(1);
#pragma unroll
    for (int i = 0; i < 4; i++)
#pragma unroll
      for (int j = 0; j < 4; j++)
        acc[i][j] = __builtin_amdgcn_mfma_f32_16x16x32_bf16(av[i], bv[j], acc[i][j], 0, 0, 0);
    __builtin_amdgcn_s_setprio(0);
    __builtin_amdgcn_s_barrier();

    // ---- phase 2: kh=0, mh=1 (4 ds_reads, bv reused) ----
#pragma unroll
    for (int i = 0; i < 4; i++)
      av[i] = *(const bf16x8*)(a0 + (((wm * 8 + 4 + i) * 2 + 0) << 9) + rdoff);
    asm volatile("" ::: "memory");
    stage(Bb + k1, K, bn, 1);
    __builtin_amdgcn_s_barrier();
    __builtin_amdgcn_s_setprio(1);
#pragma unroll
    for (int i = 0; i < 4; i++)
#pragma unroll
      for (int j = 0; j < 4; j++)
        acc[4 + i][j] = __builtin_amdgcn_mfma_f32_16x16x32_bf16(av[i], bv[j], acc[4 + i][j], 0, 0, 0);
    __builtin_amdgcn_s_setprio(0);
    // gate: retire A/B-k1(t) (staged at t-1 p1/p2); keep 4 newest stages.
    asm volatile("s_waitcnt vmcnt(8)" ::: "memory");
    __builtin_amdgcn_s_barrier();
    asm volatile("" ::: "memory");

    // ---- phase 3: kh=1, mh=0 (8 ds_reads) ----
#pragma unroll
    for (int i = 0; i < 4; i++)
      av[i] = *(const bf16x8*)(a0 + (((wm * 8 + i) * 2 + 1) << 9) + rdoff);
#pragma unroll
    for (int j = 0; j < 4; j++)
      bv[j] = *(const bf16x8*)(b0 + (((wn * 4 + j) * 2 + 1) << 9) + rdoff);
    asm volatile("" ::: "memory");
    stage(Ab + k2, lda, ac, 0);
    __builtin_amdgcn_s_barrier();
    __builtin_amdgcn_s_setprio(1);
#pragma unroll
    for (int i = 0; i < 4; i++)
#pragma unroll
      for (int j = 0; j < 4; j++)
        acc[i][j] = __builtin_amdgcn_mfma_f32_16x16x32_bf16(av[i], bv[j], acc[i][j], 0, 0, 0);
    __builtin_amdgcn_s_setprio(0);
    __builtin_amdgcn_s_barrier();

    // ---- phase 4: kh=1, mh=1 (4 ds_reads, bv reused) ----
#pragma unroll
    for (int i = 0; i < 4; i++)
      av[i] = *(const bf16x8*)(a0 + (((wm * 8 + 4 + i) * 2 + 1) << 9) + rdoff);
    asm volatile("" ::: "memory");
    stage(Bb + k2, K, bc, 0);
    __builtin_amdgcn_s_barrier();
    __builtin_amdgcn_s_setprio(1);
#pragma unroll
    for (int i = 0; i < 4; i++)
#pragma unroll
      for (int j = 0; j < 4; j++)
        acc[4 + i][j] = __builtin_amdgcn_mfma_f32_16x16x32_bf16(av[i], bv[j], acc[4 + i][j], 0, 0, 0);
    __builtin_amdgcn_s_setprio(0);
    // gate: retire A/B-k0(t+1) (staged at t p3/p4 of prior tile); keep 4.
    asm volatile("s_waitcnt vmcnt(8)" ::: "memory");
    __builtin_amdgcn_s_barrier();
    asm volatile("" ::: "memory");
  }

  // Drain remaining staged (garbage) loads before LDS reuse / exit.
  asm volatile("s_waitcnt vmcnt(0)" ::: "memory");
  __builtin_amdgcn_s_barrier();
  asm volatile("" ::: "memory");

  // Bias into acc (C/D layout: col=lane&15, row=quad*4+reg, m89-verified).
#pragma unroll
  for (int j = 0; j < 4; j++) {
    const float bj = bias[col0 + wn * 64 + j * 16 + r16];
#pragma unroll
    for (int i = 0; i < 8; i++) {
      acc[i][j][0] += bj; acc[i][j][1] += bj;
      acc[i][j][2] += bj; acc[i][j][3] += bj;
    }
  }

  if constexpr (sizeof(OT) == 2) {
    // Repack epilogue through LDS: 8 wave regions [128][64] -> 512B rows.
    bf16_t* wreg = (w < 4) ? &As[w >> 1][(w & 1) * 8192]
                           : &Bs[(w - 4) >> 1][((w - 4) & 1) * 8192];
#pragma unroll
    for (int i = 0; i < 8; i++)
#pragma unroll
      for (int j = 0; j < 4; j++)
#pragma unroll
        for (int r = 0; r < 4; r++)
          wreg[(i * 16 + quad * 4 + r) * 64 + j * 16 + r16] = (bf16_t)acc[i][j][r];
    __syncthreads();
#pragma unroll
    for (int it = 0; it < 16; it++) {
      const int r = it * 16 + (tid >> 5);
      const int c = (tid & 31) * 8;
      const int ww = ((r >> 7) << 2) + (c >> 6);
      const bf16_t* src = ((ww < 4) ? &As[ww >> 1][(ww & 1) * 8192]
                                    : &Bs[(ww - 4) >> 1][((ww - 4) & 1) * 8192])
                          + (r & 127) * 64 + (c & 63);
      *(bf16x8*)((bf16_t*)C + (row0 + r) * ldc + col0 + c) = *(const bf16x8*)src;
    }
  } else {
    // fp32 output: 16-lane x 4B = 64B segments, no amplification; direct.
#pragma unroll
    for (int j = 0; j < 4; j++) {
      const long col = col0 + wn * 64 + j * 16 + r16;
#pragma unroll
      for (int i = 0; i < 8; i++) {
        const long row = row0 + wm * 128 + i * 16 + quad * 4;
#pragma unroll
        for (int r = 0; r < 4; r++)
          C[(row + r) * ldc + col] = (OT)acc[i][j][r];
      }
    }
  }
}

// ---------------------------------------------------------------------------
// Weight transpose+convert: in fp32 [R][C] -> out bf16 [C][R]. 32x32 tiles,
// block (32,8). out may point into a stacked [N_tot,K] buffer.
// ---------------------------------------------------------------------------
__global__ void transpose_f32_bf16(const float* __restrict__ in, bf16_t* __restrict__ out,
                                   int R, int C)
{
  __shared__ bf16_t tile[32][33];
  const int cb = blockIdx.x * 32, rb = blockIdx.y * 32;
  const int tx = threadIdx.x, ty = threadIdx.y;
#pragma unroll
  for (int i = 0; i < 32; i += 8)
    tile[ty + i][tx] = (bf16_t)in[(size_t)(rb + ty + i) * C + cb + tx];
  __syncthreads();
#pragma unroll
  for (int i = 0; i < 32; i += 8)
    out[(size_t)(cb + ty + i) * R + rb + tx] = tile[tx][ty + i];
}

// ---------------------------------------------------------------------------
// fp32 -> bf16 elementwise convert, 8 elems/thread. n % 8 == 0.
// ---------------------------------------------------------------------------
__global__ void cvt_f32_bf16(const float* __restrict__ in, bf16_t* __restrict__ out, long n)
{
  const long i = ((long)blockIdx.x * blockDim.x + threadIdx.x) * 8;
  if (i >= n) return;
  const float4 a = *(const float4*)(in + i);
  const float4 b = *(const float4*)(in + i + 4);
  bf16x8 o;
  o[0] = (bf16_t)a.x; o[1] = (bf16_t)a.y; o[2] = (bf16_t)a.z; o[3] = (bf16_t)a.w;
  o[4] = (bf16_t)b.x; o[5] = (bf16_t)b.y; o[6] = (bf16_t)b.z; o[7] = (bf16_t)b.w;
  *(bf16x8*)(out + i) = o;
}

// ---------------------------------------------------------------------------
// Concatenate biases for the merged GEMMs. 9216 threads.
// b1[2048]={bc,bckv,bkr} b2[3072]={bcq,bqr} b3[4096]={bck,bv}
// ---------------------------------------------------------------------------
__global__ void concat_bias(const float* bc, const float* bckv, const float* bkr,
                            const float* bcq, const float* bqr,
                            const float* bck, const float* bv,
                            float* b1, float* b2, float* b3)
{
  const int t = blockIdx.x * 256 + threadIdx.x;
  if (t < 2048) {
    b1[t] = (t < 512) ? bc[t] : (t < 1024) ? bckv[t - 512] : bkr[t - 1024];
  } else if (t < 5120) {
    const int u = t - 2048;
    b2[u] = (u < 2048) ? bcq[u] : bqr[u - 2048];
  } else if (t < 9216) {
    const int u = t - 5120;
    b3[u] = (u < 2048) ? bck[u] : bv[u - 2048];
  }
}

// ---------------------------------------------------------------------------
// Fused RoPE + per-token 16x16 head attention over the fused buffers.
// fused1[8192][2048]: cols 1024.. = kr(pre-rope)
// fused2[8192][3072]: cols 0..2047 = q (overwritten with output), 2048.. = qr
// fused3[8192][4096]: cols 0..2047 = k, 2048.. = v
// ---------------------------------------------------------------------------
__global__ __launch_bounds__(256) void attn_rope(
    const bf16_t* __restrict__ f1, bf16_t* f2, const bf16_t* __restrict__ f3)
{
  const int tok = blockIdx.x;
  const int pos = tok & 4095;   // position within sequence (S=4096)
  const int tid = threadIdx.x;

  __shared__ __align__(16) float qf[16 * 204];
  __shared__ __align__(16) float kf[16 * 204];
  __shared__ __align__(16) float vf[16 * 132];
  __shared__ float sc[256];

  const bf16_t* q  = f2 + (size_t)tok * 3072;
  const bf16_t* qr = q + 2048;
  const bf16_t* k  = f3 + (size_t)tok * 4096;
  const bf16_t* v  = k + 2048;
  const bf16_t* kr = f1 + (size_t)tok * 2048 + 1024;

  {
    const int h = tid >> 4, d = (tid & 15) * 8;
    bf16x8 xq = *(const bf16x8*)(q + tid * 8);
    bf16x8 xk = *(const bf16x8*)(k + tid * 8);
    bf16x8 xv = *(const bf16x8*)(v + tid * 8);
    float* qd = qf + h * 204 + d;
    float* kd = kf + h * 204 + d;
    float* vd = vf + h * 132 + d;
#pragma unroll
    for (int e = 0; e < 8; e++) {
      qd[e] = (float)xq[e];
      kd[e] = (float)xk[e];
      vd[e] = (float)xv[e];
    }
  }

  // RoPE: inv_freq[j] = 10000^(-j/32) = 2^(-j*log2(10000)/32)
  for (int p = tid; p < 512; p += 256) {
    const int h = p >> 5, j = p & 31;
    const float x1 = (float)qr[h * 64 + j];
    const float x2 = (float)qr[h * 64 + j + 32];
    const float y1 = (float)kr[h * 64 + j];
    const float y2 = (float)kr[h * 64 + j + 32];
    const float ang = (float)pos * exp2f((float)j * -0.41524101186092029f);
    float sn, cs;
    sincosf(ang, &sn, &cs);
    qf[h * 204 + 128 + j] = x1 * cs - x2 * sn;
    qf[h * 204 + 160 + j] = x2 * cs + x1 * sn;
    kf[h * 204 + 128 + j] = y1 * cs - y2 * sn;
    kf[h * 204 + 160 + j] = y2 * cs + y1 * sn;
  }
  __syncthreads();

  {
    const int i = tid >> 4, j = tid & 15;
    const float4* qrow = (const float4*)(qf + i * 204);
    const float4* krow = (const float4*)(kf + j * 204);
    float d0 = 0.f, d1 = 0.f, d2 = 0.f, d3 = 0.f;
#pragma unroll 8
    for (int dd = 0; dd < 48; dd++) {
      const float4 a = qrow[dd], b = krow[dd];
      d0 = fmaf(a.x, b.x, d0);
      d1 = fmaf(a.y, b.y, d1);
      d2 = fmaf(a.z, b.z, d2);
      d3 = fmaf(a.w, b.w, d3);
    }
    const float s = (d0 + d1 + d2 + d3) * 0.07216878364870323f; // 1/sqrt(192)
    float m = s;
    m = fmaxf(m, __shfl_xor(m, 1));
    m = fmaxf(m, __shfl_xor(m, 2));
    m = fmaxf(m, __shfl_xor(m, 4));
    m = fmaxf(m, __shfl_xor(m, 8));
    const float e = __expf(s - m);
    float sum = e;
    sum += __shfl_xor(sum, 1);
    sum += __shfl_xor(sum, 2);
    sum += __shfl_xor(sum, 4);
    sum += __shfl_xor(sum, 8);
    sc[i * 16 + j] = e / sum;
  }
  __syncthreads();

  {
    const int i = tid >> 4, dp = (tid & 15) * 8;
    float4 a0 = {0.f, 0.f, 0.f, 0.f}, a1 = {0.f, 0.f, 0.f, 0.f};
#pragma unroll
    for (int j = 0; j < 16; j++) {
      const float a = sc[i * 16 + j];
      const float4* vrow = (const float4*)(vf + j * 132 + dp);
      const float4 v0 = vrow[0], v1 = vrow[1];
      a0.x = fmaf(a, v0.x, a0.x);
      a0.y = fmaf(a, v0.y, a0.y);
      a0.z = fmaf(a, v0.z, a0.z);
      a0.w = fmaf(a, v0.w, a0.w);
      a1.x = fmaf(a, v1.x, a1.x);
      a1.y = fmaf(a, v1.y, a1.y);
      a1.z = fmaf(a, v1.z, a1.z);
      a1.w = fmaf(a, v1.w, a1.w);
    }
    bf16x8 o;
    o[0] = (bf16_t)a0.x; o[1] = (bf16_t)a0.y; o[2] = (bf16_t)a0.z; o[3] = (bf16_t)a0.w;
    o[4] = (bf16_t)a1.x; o[5] = (bf16_t)a1.y; o[6] = (bf16_t)a1.z; o[7] = (bf16_t)a1.w;
    // write over q columns of fused2 (this block read its own q above)
    *(bf16x8*)(f2 + (size_t)tok * 3072 + i * 128 + dp) = o;
  }
}

// ---------------------------------------------------------------------------
extern "C" void kernel_launch(void* const* d_in, const int* in_sizes, int n_in,
                              void* d_out, int out_size, void* d_ws, size_t ws_size,
                              hipStream_t stream)
{
  (void)in_sizes; (void)n_in; (void)out_size; (void)ws_size;

  const float* h_t  = (const float*)d_in[0];
  const float* Wc   = (const float*)d_in[1];
  const float* bc   = (const float*)d_in[2];
  const float* Wcq  = (const float*)d_in[3];
  const float* bcq  = (const float*)d_in[4];
  const float* Wqr  = (const float*)d_in[5];
  const float* bqr  = (const float*)d_in[6];
  const float* Wckv = (const float*)d_in[7];
  const float* bckv = (const float*)d_in[8];
  const float* Wck  = (const float*)d_in[9];
  const float* bck  = (const float*)d_in[10];
  const float* Wkr  = (const float*)d_in[11];
  const float* bkr  = (const float*)d_in[12];
  const float* Wv   = (const float*)d_in[13];
  const float* bv   = (const float*)d_in[14];
  const float* Wo   = (const float*)d_in[15];
  const float* bo   = (const float*)d_in[16];

  bf16_t* ws = (bf16_t*)d_ws;
  // ws layout (bf16 elems) — total 87,556,096 = 175,112,192 B (proven fit R4)
  bf16_t* W1T    = ws + 0;         // [2048,2048] rows: WcT 0-511, WckvT 512-1023, WkrT 1024-2047
  bf16_t* W2T    = ws + 4194304;   // [3072,512]  rows: WcqT 0-2047, WqrT 2048-3071
  bf16_t* W3T    = ws + 5767168;   // [4096,512]  rows: WckT 0-2047, WvT 2048-4095
  bf16_t* WoT    = ws + 7864320;   // [2048,2048]
  bf16_t* fused1 = ws + 12058624;  // [8192,2048] cq|ckv|kr_pre
  bf16_t* fused2 = ws + 28835840;  // [8192,3072] q|qr  (q cols become attn out)
  bf16_t* fused3 = ws + 54001664;  // [8192,4096] k|v

  // d_out as scratch until the final GEMM: bf16 h_t copy + concat'd biases
  bf16_t* hbf = (bf16_t*)d_out;                          // 16,777,216 elems (33.5 MB)
  float*  b1  = (float*)((char*)d_out + 33554432);       // 2048 f
  float*  b2  = b1 + 2048;                               // 3072 f
  float*  b3  = b2 + 3072;                               // 4096 f

  const dim3 tb(32, 8);
  transpose_f32_bf16<<<dim3(16, 64), tb, 0, stream>>>(Wc,   W1T,                2048, 512);
  transpose_f32_bf16<<<dim3(16, 64), tb, 0, stream>>>(Wckv, W1T + 512  * 2048,  2048, 512);
  transpose_f32_bf16<<<dim3(32, 64), tb, 0, stream>>>(Wkr,  W1T + 1024 * 2048,  2048, 1024);
  transpose_f32_bf16<<<dim3(64, 16), tb, 0, stream>>>(Wcq,  W2T,                512, 2048);
  transpose_f32_bf16<<<dim3(32, 16), tb, 0, stream>>>(Wqr,  W2T + 2048 * 512,   512, 1024);
  transpose_f32_bf16<<<dim3(64, 16), tb, 0, stream>>>(Wck,  W3T,                512, 2048);
  transpose_f32_bf16<<<dim3(64, 16), tb, 0, stream>>>(Wv,   W3T + 2048 * 512,   512, 2048);
  transpose_f32_bf16<<<dim3(64, 64), tb, 0, stream>>>(Wo,   WoT,                2048, 2048);
  concat_bias<<<36, 256, 0, stream>>>(bc, bckv, bkr, bcq, bqr, bck, bv, b1, b2, b3);
  cvt_f32_bf16<<<8192, 256, 0, stream>>>(h_t, hbf, 16777216L);

  // stage 1: [cq|ckv|kr_pre] = hbf @ [Wc|Wckv|Wkr]   M=8192 N=2048 K=2048
  gemm_bt256<bf16_t><<<dim3(8, 32), 512, 0, stream>>>(hbf, 2048, W1T, b1, fused1, 2048, 8192, 2048, 2048);
  // stage 2a: [q|qr] = cq @ [Wcq|Wqr]                M=8192 N=3072 K=512
  gemm_bt256<bf16_t><<<dim3(12, 32), 512, 0, stream>>>(fused1, 2048, W2T, b2, fused2, 3072, 8192, 3072, 512);
  // stage 2b: [k|v] = ckv @ [Wck|Wv]                 M=8192 N=4096 K=512
  gemm_bt256<bf16_t><<<dim3(16, 32), 512, 0, stream>>>(fused1 + 512, 2048, W3T, b3, fused3, 4096, 8192, 4096, 512);

  // fused rope + attention (output over q cols of fused2)
  attn_rope<<<8192, 256, 0, stream>>>(fused1, fused2, fused3);

  // output projection -> fp32 d_out                  M=8192 N=2048 K=2048
  gemm_bt256<float><<<dim3(8, 32), 512, 0, stream>>>(fused2, 3072, WoT, bo, (float*)d_out, 2048, 8192, 2048, 2048);
}

// Round 4
// 482.299 us; speedup vs baseline: 1.1439x; 1.0266x over previous
//
#include <hip/hip_runtime.h>
#include <hip/hip_bf16.h>
#include <stdint.h>

// MLA fused pipeline, fp32 I/O, bf16 MFMA internals.
// R10: exact m201 phase idiom. R7/R8/R9 all plateau at ~100us / 28% MfmaUtil
// -> phase body serializes (issue reads, barrier, drain, MFMA, barrier).
// Changes vs R9:
//  - Phase = {reads | stage | barrier | s_waitcnt lgkmcnt(0) | setprio(1)
//    16xMFMA setprio(0) | [gate vmcnt(8)] | barrier}. Explicit lgkmcnt(0),
//    NO sched_barrier (m141), no extra "" memory fences. Waves hit barrier-1
//    right after issuing reads; CU-wide LDS drain overlaps MFMA of waves
//    that drain first.
//  - 2-K-tile / 8-phase unrolled body: buffer roles constant (E=buf0,
//    O=buf1), stages at every phase, gates (vmcnt(8)) at p2/p4/p6/p8,
//    uniform 6-phase stage->read lead. Ledger verified; prologue = 6 stages
//    + vmcnt(8).
//  - Zero per-phase address VALU: 4 running global pointers (A/B x subtile
//    half), advanced +=128 elems per iteration; all stage srcs/dsts are
//    ptr + literal (fold into instruction offsets). Tail prefetches run
//    <=448B past A/BT ends instead of clamping (all call sites verified
//    in-bounds of ws/d_out allocations).
//  - T1 XCD-chunked blockIdx swizzle (nwg%8==0 for all grids here).
// Keeps: st_16x32 swizzled LDS (conflicts==0 verified R8/R9), counted vmcnt
// never 0 in loop, bf16 LDS-repack epilogue, same per-acc K summation order.

typedef __bf16 bf16_t;
typedef __bf16 bf16x8 __attribute__((ext_vector_type(8)));
typedef float f32x4 __attribute__((ext_vector_type(4)));

__device__ __forceinline__ void async_copy16(const void* g, void* l) {
  __builtin_amdgcn_global_load_lds(
      (__attribute__((address_space(1))) void*)(void*)g,
      (__attribute__((address_space(3))) void*)l, 16, 0, 0);
}

// ---------------------------------------------------------------------------
// GEMM: C[M,N](ldc) = A[M,K](lda) @ BT[N,K]^T + bias. bf16 in, OT out.
// 256x256 tile, BK=64 dbuf, 512 threads (8 waves 2Mx4N, 128x64 each).
// M%256==0, N%256==0, K%128==0. A and BT must be readable 448B past end
// (tail prefetch; never consumed). grid.x*grid.y % 8 == 0.
// ---------------------------------------------------------------------------
template <typename OT>
__global__ __launch_bounds__(512, 2) void gemm_bt256(
    const bf16_t* __restrict__ A, long lda,
    const bf16_t* __restrict__ BT,
    const float* __restrict__ bias,
    OT* __restrict__ C, long ldc,
    int M, int N, int K)
{
  __shared__ __align__(16) bf16_t As[2][16384];   // [buf][32 subtiles x 512]
  __shared__ __align__(16) bf16_t Bs[2][16384];

  const int tid  = threadIdx.x;
  const int lane = tid & 63;
  const int w    = tid >> 6;
  const int wm   = w >> 2, wn = w & 3;            // wave grid 2 x 4
  const int quad = lane >> 4, r16 = lane & 15;

  // T1: XCD-chunked swizzle (XCD = dispatch_id % 8 heuristic; bijective
  // since nwg % 8 == 0 for all grids used here).
  const int nwg = gridDim.x * gridDim.y;
  int wg = blockIdx.y * gridDim.x + blockIdx.x;
  wg = (wg & 7) * (nwg >> 3) + (wg >> 3);
  const int bx = wg % gridDim.x, by = wg / gridDim.x;
  const long row0 = (long)by * 256;
  const long col0 = (long)bx * 256;

  const bf16_t* Ab = A + row0 * lda;
  const bf16_t* Bb = BT + col0 * (long)K;

  // ds_read element offset (st_16x32 swizzle): logical (r=R*16+r16,
  // k=Kc*32+quad*8..) -> elem (R*2+Kc)*512 + r16*32 + (quad*8 ^ (r16&8?16:0))
  const int rdoff = r16 * 32 + ((quad * 8) ^ ((r16 & 8) ? 16 : 0));

  // staging: one global_load_lds fills one 1024B subtile linearly; lane l
  // holds (row l>>2, 16B chunk l&3); inverse swizzle on the global source.
  const int srin = lane >> 2;
  const int sksw = ((lane & 3) * 8) ^ ((lane & 32) ? 16 : 0);

  // Running per-wave global pointers: subtile-half s=0 (rows w*16..) and
  // s=1 (rows (8+w)*16..). Advanced += 128 elems (2 K-tiles) per iteration.
  const bf16_t* pA0 = Ab + (long)(w * 16 + srin) * lda + sksw;
  const bf16_t* pA1 = Ab + (long)((8 + w) * 16 + srin) * lda + sksw;
  const bf16_t* pB0 = Bb + (long)(w * 16 + srin) * K + sksw;
  const bf16_t* pB1 = Bb + (long)((8 + w) * 16 + srin) * K + sksw;

  f32x4 acc[8][4];
#pragma unroll
  for (int i = 0; i < 8; i++)
#pragma unroll
    for (int j = 0; j < 4; j++)
      acc[i][j] = (f32x4){0.f, 0.f, 0.f, 0.f};

  bf16x8 av[4], bv[4];

  // stage one operand-half: koff/Kc compile-time -> ptr+literal addresses.
#define STA(koff, dbuf, Kc)                                                  \
  async_copy16(pA0 + (koff) + (Kc) * 32, &As[dbuf][(w * 2 + (Kc)) << 9]);    \
  async_copy16(pA1 + (koff) + (Kc) * 32, &As[dbuf][((8 + w) * 2 + (Kc)) << 9])
#define STB(koff, dbuf, Kc)                                                  \
  async_copy16(pB0 + (koff) + (Kc) * 32, &Bs[dbuf][(w * 2 + (Kc)) << 9]);    \
  async_copy16(pB1 + (koff) + (Kc) * 32, &Bs[dbuf][((8 + w) * 2 + (Kc)) << 9])

#define PHASE(RBUF, KH, MH, LOADB, STAGE_STMT, GATE)                         \
  {                                                                          \
    _Pragma("unroll")                                                        \
    for (int i_ = 0; i_ < 4; i_++)                                           \
      av[i_] = *(const bf16x8*)(&As[RBUF][0] +                               \
                (((wm * 8 + (MH) * 4 + i_) * 2 + (KH)) << 9) + rdoff);       \
    if (LOADB) {                                                             \
      _Pragma("unroll")                                                      \
      for (int j_ = 0; j_ < 4; j_++)                                         \
        bv[j_] = *(const bf16x8*)(&Bs[RBUF][0] +                             \
                  (((wn * 4 + j_) * 2 + (KH)) << 9) + rdoff);                \
    }                                                                        \
    STAGE_STMT;                                                              \
    __builtin_amdgcn_s_barrier();                                            \
    asm volatile("s_waitcnt lgkmcnt(0)" ::: "memory");                       \
    __builtin_amdgcn_s_setprio(1);                                           \
    _Pragma("unroll")                                                        \
    for (int i_ = 0; i_ < 4; i_++)                                           \
      _Pragma("unroll")                                                      \
      for (int j_ = 0; j_ < 4; j_++)                                         \
        acc[(MH) * 4 + i_][j_] = __builtin_amdgcn_mfma_f32_16x16x32_bf16(    \
            av[i_], bv[j_], acc[(MH) * 4 + i_][j_], 0, 0, 0);                \
    __builtin_amdgcn_s_setprio(0);                                           \
    if (GATE) { asm volatile("s_waitcnt vmcnt(8)" ::: "memory"); }           \
    __builtin_amdgcn_s_barrier();                                            \
  }

  // Prologue: E0 kh0, E0 kh1, O0 kh0 (6 stages = 12 loads), retire E0-kh0.
  STA(0, 0, 0);
  STB(0, 0, 0);
  STA(0, 0, 1);
  STB(0, 0, 1);
  STA(64, 1, 0);
  STB(64, 1, 0);
  asm volatile("s_waitcnt vmcnt(8)" ::: "memory");
  __builtin_amdgcn_s_barrier();

  const int NI = K >> 7;                          // 2 K-tiles per iteration
  for (int it = 0; it < NI; it++) {
    // tiles E (buf0) phases 1-4, O (buf1) phases 5-8; stage lead 6 phases.
    PHASE(0, 0, 0, true,  STA(64, 1, 1),  false)  // p1: stage A-O-kh1
    PHASE(0, 0, 1, false, STB(64, 1, 1),  true)   // p2: B-O-kh1; gate
    PHASE(0, 1, 0, true,  STA(128, 0, 0), false)  // p3: A-T2-kh0
    PHASE(0, 1, 1, false, STB(128, 0, 0), true)   // p4: gate
    PHASE(1, 0, 0, true,  STA(128, 0, 1), false)  // p5: A-T2-kh1
    PHASE(1, 0, 1, false, STB(128, 0, 1), true)   // p6: gate
    PHASE(1, 1, 0, true,  STA(192, 1, 0), false)  // p7: A-T3-kh0
    PHASE(1, 1, 1, false, STB(192, 1, 0), true)   // p8: gate
    pA0 += 128; pA1 += 128; pB0 += 128; pB1 += 128;
  }
#undef PHASE
#undef STA
#undef STB

  // Drain remaining staged (tail garbage) loads before LDS reuse / exit.
  asm volatile("s_waitcnt vmcnt(0)" ::: "memory");
  __builtin_amdgcn_s_barrier();

  // Bias into acc (C/D layout: col=lane&15, row=quad*4+reg, m89-verified).
#pragma unroll
  for (int j = 0; j < 4; j++) {
    const float bj = bias[col0 + wn * 64 + j * 16 + r16];
#pragma unroll
    for (int i = 0; i < 8; i++) {
      acc[i][j][0] += bj; acc[i][j][1] += bj;
      acc[i][j][2] += bj; acc[i][j][3] += bj;
    }
  }

  if constexpr (sizeof(OT) == 2) {
    // Repack epilogue through LDS: 8 wave regions [128][64] -> 512B rows.
    bf16_t* wreg = (w < 4) ? &As[w >> 1][(w & 1) * 8192]
                           : &Bs[(w - 4) >> 1][((w - 4) & 1) * 8192];
#pragma unroll
    for (int i = 0; i < 8; i++)
#pragma unroll
      for (int j = 0; j < 4; j++)
#pragma unroll
        for (int r = 0; r < 4; r++)
          wreg[(i * 16 + quad * 4 + r) * 64 + j * 16 + r16] = (bf16_t)acc[i][j][r];
    __syncthreads();
#pragma unroll
    for (int itr = 0; itr < 16; itr++) {
      const int r = itr * 16 + (tid >> 5);
      const int c = (tid & 31) * 8;
      const int ww = ((r >> 7) << 2) + (c >> 6);
      const bf16_t* src = ((ww < 4) ? &As[ww >> 1][(ww & 1) * 8192]
                                    : &Bs[(ww - 4) >> 1][((ww - 4) & 1) * 8192])
                          + (r & 127) * 64 + (c & 63);
      *(bf16x8*)((bf16_t*)C + (row0 + r) * ldc + col0 + c) = *(const bf16x8*)src;
    }
  } else {
    // fp32 output: 16-lane x 4B = 64B segments, no amplification; direct.
#pragma unroll
    for (int j = 0; j < 4; j++) {
      const long col = col0 + wn * 64 + j * 16 + r16;
#pragma unroll
      for (int i = 0; i < 8; i++) {
        const long row = row0 + wm * 128 + i * 16 + quad * 4;
#pragma unroll
        for (int r = 0; r < 4; r++)
          C[(row + r) * ldc + col] = (OT)acc[i][j][r];
      }
    }
  }
}

// ---------------------------------------------------------------------------
// Weight transpose+convert: in fp32 [R][C] -> out bf16 [C][R]. 32x32 tiles,
// block (32,8). out may point into a stacked [N_tot,K] buffer.
// ---------------------------------------------------------------------------
__global__ void transpose_f32_bf16(const float* __restrict__ in, bf16_t* __restrict__ out,
                                   int R, int C)
{
  __shared__ bf16_t tile[32][33];
  const int cb = blockIdx.x * 32, rb = blockIdx.y * 32;
  const int tx = threadIdx.x, ty = threadIdx.y;
#pragma unroll
  for (int i = 0; i < 32; i += 8)
    tile[ty + i][tx] = (bf16_t)in[(size_t)(rb + ty + i) * C + cb + tx];
  __syncthreads();
#pragma unroll
  for (int i = 0; i < 32; i += 8)
    out[(size_t)(cb + ty + i) * R + rb + tx] = tile[tx][ty + i];
}

// ---------------------------------------------------------------------------
// fp32 -> bf16 elementwise convert, 8 elems/thread. n % 8 == 0.
// ---------------------------------------------------------------------------
__global__ void cvt_f32_bf16(const float* __restrict__ in, bf16_t* __restrict__ out, long n)
{
  const long i = ((long)blockIdx.x * blockDim.x + threadIdx.x) * 8;
  if (i >= n) return;
  const float4 a = *(const float4*)(in + i);
  const float4 b = *(const float4*)(in + i + 4);
  bf16x8 o;
  o[0] = (bf16_t)a.x; o[1] = (bf16_t)a.y; o[2] = (bf16_t)a.z; o[3] = (bf16_t)a.w;
  o[4] = (bf16_t)b.x; o[5] = (bf16_t)b.y; o[6] = (bf16_t)b.z; o[7] = (bf16_t)b.w;
  *(bf16x8*)(out + i) = o;
}

// ---------------------------------------------------------------------------
// Concatenate biases for the merged GEMMs. 9216 threads.
// b1[2048]={bc,bckv,bkr} b2[3072]={bcq,bqr} b3[4096]={bck,bv}
// ---------------------------------------------------------------------------
__global__ void concat_bias(const float* bc, const float* bckv, const float* bkr,
                            const float* bcq, const float* bqr,
                            const float* bck, const float* bv,
                            float* b1, float* b2, float* b3)
{
  const int t = blockIdx.x * 256 + threadIdx.x;
  if (t < 2048) {
    b1[t] = (t < 512) ? bc[t] : (t < 1024) ? bckv[t - 512] : bkr[t - 1024];
  } else if (t < 5120) {
    const int u = t - 2048;
    b2[u] = (u < 2048) ? bcq[u] : bqr[u - 2048];
  } else if (t < 9216) {
    const int u = t - 5120;
    b3[u] = (u < 2048) ? bck[u] : bv[u - 2048];
  }
}

// ---------------------------------------------------------------------------
// Fused RoPE + per-token 16x16 head attention over the fused buffers.
// fused1[8192][2048]: cols 1024.. = kr(pre-rope)
// fused2[8192][3072]: cols 0..2047 = q (overwritten with output), 2048.. = qr
// fused3[8192][4096]: cols 0..2047 = k, 2048.. = v
// ---------------------------------------------------------------------------
__global__ __launch_bounds__(256) void attn_rope(
    const bf16_t* __restrict__ f1, bf16_t* f2, const bf16_t* __restrict__ f3)
{
  const int tok = blockIdx.x;
  const int pos = tok & 4095;   // position within sequence (S=4096)
  const int tid = threadIdx.x;

  __shared__ __align__(16) float qf[16 * 204];
  __shared__ __align__(16) float kf[16 * 204];
  __shared__ __align__(16) float vf[16 * 132];
  __shared__ float sc[256];

  const bf16_t* q  = f2 + (size_t)tok * 3072;
  const bf16_t* qr = q + 2048;
  const bf16_t* k  = f3 + (size_t)tok * 4096;
  const bf16_t* v  = k + 2048;
  const bf16_t* kr = f1 + (size_t)tok * 2048 + 1024;

  {
    const int h = tid >> 4, d = (tid & 15) * 8;
    bf16x8 xq = *(const bf16x8*)(q + tid * 8);
    bf16x8 xk = *(const bf16x8*)(k + tid * 8);
    bf16x8 xv = *(const bf16x8*)(v + tid * 8);
    float* qd = qf + h * 204 + d;
    float* kd = kf + h * 204 + d;
    float* vd = vf + h * 132 + d;
#pragma unroll
    for (int e = 0; e < 8; e++) {
      qd[e] = (float)xq[e];
      kd[e] = (float)xk[e];
      vd[e] = (float)xv[e];
    }
  }

  // RoPE: inv_freq[j] = 10000^(-j/32) = 2^(-j*log2(10000)/32)
  for (int p = tid; p < 512; p += 256) {
    const int h = p >> 5, j = p & 31;
    const float x1 = (float)qr[h * 64 + j];
    const float x2 = (float)qr[h * 64 + j + 32];
    const float y1 = (float)kr[h * 64 + j];
    const float y2 = (float)kr[h * 64 + j + 32];
    const float ang = (float)pos * exp2f((float)j * -0.41524101186092029f);
    float sn, cs;
    sincosf(ang, &sn, &cs);
    qf[h * 204 + 128 + j] = x1 * cs - x2 * sn;
    qf[h * 204 + 160 + j] = x2 * cs + x1 * sn;
    kf[h * 204 + 128 + j] = y1 * cs - y2 * sn;
    kf[h * 204 + 160 + j] = y2 * cs + y1 * sn;
  }
  __syncthreads();

  {
    const int i = tid >> 4, j = tid & 15;
    const float4* qrow = (const float4*)(qf + i * 204);
    const float4* krow = (const float4*)(kf + j * 204);
    float d0 = 0.f, d1 = 0.f, d2 = 0.f, d3 = 0.f;
#pragma unroll 8
    for (int dd = 0; dd < 48; dd++) {
      const float4 a = qrow[dd], b = krow[dd];
      d0 = fmaf(a.x, b.x, d0);
      d1 = fmaf(a.y, b.y, d1);
      d2 = fmaf(a.z, b.z, d2);
      d3 = fmaf(a.w, b.w, d3);
    }
    const float s = (d0 + d1 + d2 + d3) * 0.07216878364870323f; // 1/sqrt(192)
    float m = s;
    m = fmaxf(m, __shfl_xor(m, 1));
    m = fmaxf(m, __shfl_xor(m, 2));
    m = fmaxf(m, __shfl_xor(m, 4));
    m = fmaxf(m, __shfl_xor(m, 8));
    const float e = __expf(s - m);
    float sum = e;
    sum += __shfl_xor(sum, 1);
    sum += __shfl_xor(sum, 2);
    sum += __shfl_xor(sum, 4);
    sum += __shfl_xor(sum, 8);
    sc[i * 16 + j] = e / sum;
  }
  __syncthreads();

  {
    const int i = tid >> 4, dp = (tid & 15) * 8;
    float4 a0 = {0.f, 0.f, 0.f, 0.f}, a1 = {0.f, 0.f, 0.f, 0.f};
#pragma unroll
    for (int j = 0; j < 16; j++) {
      const float a = sc[i * 16 + j];
      const float4* vrow = (const float4*)(vf + j * 132 + dp);
      const float4 v0 = vrow[0], v1 = vrow[1];
      a0.x = fmaf(a, v0.x, a0.x);
      a0.y = fmaf(a, v0.y, a0.y);
      a0.z = fmaf(a, v0.z, a0.z);
      a0.w = fmaf(a, v0.w, a0.w);
      a1.x = fmaf(a, v1.x, a1.x);
      a1.y = fmaf(a, v1.y, a1.y);
      a1.z = fmaf(a, v1.z, a1.z);
      a1.w = fmaf(a, v1.w, a1.w);
    }
    bf16x8 o;
    o[0] = (bf16_t)a0.x; o[1] = (bf16_t)a0.y; o[2] = (bf16_t)a0.z; o[3] = (bf16_t)a0.w;
    o[4] = (bf16_t)a1.x; o[5] = (bf16_t)a1.y; o[6] = (bf16_t)a1.z; o[7] = (bf16_t)a1.w;
    // write over q columns of fused2 (this block read its own q above)
    *(bf16x8*)(f2 + (size_t)tok * 3072 + i * 128 + dp) = o;
  }
}

// ---------------------------------------------------------------------------
extern "C" void kernel_launch(void* const* d_in, const int* in_sizes, int n_in,
                              void* d_out, int out_size, void* d_ws, size_t ws_size,
                              hipStream_t stream)
{
  (void)in_sizes; (void)n_in; (void)out_size; (void)ws_size;

  const float* h_t  = (const float*)d_in[0];
  const float* Wc   = (const float*)d_in[1];
  const float* bc   = (const float*)d_in[2];
  const float* Wcq  = (const float*)d_in[3];
  const float* bcq  = (const float*)d_in[4];
  const float* Wqr  = (const float*)d_in[5];
  const float* bqr  = (const float*)d_in[6];
  const float* Wckv = (const float*)d_in[7];
  const float* bckv = (const float*)d_in[8];
  const float* Wck  = (const float*)d_in[9];
  const float* bck  = (const float*)d_in[10];
  const float* Wkr  = (const float*)d_in[11];
  const float* bkr  = (const float*)d_in[12];
  const float* Wv   = (const float*)d_in[13];
  const float* bv   = (const float*)d_in[14];
  const float* Wo   = (const float*)d_in[15];
  const float* bo   = (const float*)d_in[16];

  bf16_t* ws = (bf16_t*)d_ws;
  // ws layout (bf16 elems) — total 87,556,096 = 175,112,192 B (proven fit R4)
  bf16_t* W1T    = ws + 0;         // [2048,2048] rows: WcT 0-511, WckvT 512-1023, WkrT 1024-2047
  bf16_t* W2T    = ws + 4194304;   // [3072,512]  rows: WcqT 0-2047, WqrT 2048-3071
  bf16_t* W3T    = ws + 5767168;   // [4096,512]  rows: WckT 0-2047, WvT 2048-4095
  bf16_t* WoT    = ws + 7864320;   // [2048,2048]
  bf16_t* fused1 = ws + 12058624;  // [8192,2048] cq|ckv|kr_pre
  bf16_t* fused2 = ws + 28835840;  // [8192,3072] q|qr  (q cols become attn out)
  bf16_t* fused3 = ws + 54001664;  // [8192,4096] k|v

  // d_out as scratch until the final GEMM: bf16 h_t copy + concat'd biases
  bf16_t* hbf = (bf16_t*)d_out;                          // 16,777,216 elems (33.5 MB)
  float*  b1  = (float*)((char*)d_out + 33554432);       // 2048 f
  float*  b2  = b1 + 2048;                               // 3072 f
  float*  b3  = b2 + 3072;                               // 4096 f

  const dim3 tb(32, 8);
  transpose_f32_bf16<<<dim3(16, 64), tb, 0, stream>>>(Wc,   W1T,                2048, 512);
  transpose_f32_bf16<<<dim3(16, 64), tb, 0, stream>>>(Wckv, W1T + 512  * 2048,  2048, 512);
  transpose_f32_bf16<<<dim3(32, 64), tb, 0, stream>>>(Wkr,  W1T + 1024 * 2048,  2048, 1024);
  transpose_f32_bf16<<<dim3(64, 16), tb, 0, stream>>>(Wcq,  W2T,                512, 2048);
  transpose_f32_bf16<<<dim3(32, 16), tb, 0, stream>>>(Wqr,  W2T + 2048 * 512,   512, 1024);
  transpose_f32_bf16<<<dim3(64, 16), tb, 0, stream>>>(Wck,  W3T,                512, 2048);
  transpose_f32_bf16<<<dim3(64, 16), tb, 0, stream>>>(Wv,   W3T + 2048 * 512,   512, 2048);
  transpose_f32_bf16<<<dim3(64, 64), tb, 0, stream>>>(Wo,   WoT,                2048, 2048);
  concat_bias<<<36, 256, 0, stream>>>(bc, bckv, bkr, bcq, bqr, bck, bv, b1, b2, b3);
  cvt_f32_bf16<<<8192, 256, 0, stream>>>(h_t, hbf, 16777216L);

  // stage 1: [cq|ckv|kr_pre] = hbf @ [Wc|Wckv|Wkr]   M=8192 N=2048 K=2048
  gemm_bt256<bf16_t><<<dim3(8, 32), 512, 0, stream>>>(hbf, 2048, W1T, b1, fused1, 2048, 8192, 2048, 2048);
  // stage 2a: [q|qr] = cq @ [Wcq|Wqr]                M=8192 N=3072 K=512
  gemm_bt256<bf16_t><<<dim3(12, 32), 512, 0, stream>>>(fused1, 2048, W2T, b2, fused2, 3072, 8192, 3072, 512);
  // stage 2b: [k|v] = ckv @ [Wck|Wv]                 M=8192 N=4096 K=512
  gemm_bt256<bf16_t><<<dim3(16, 32), 512, 0, stream>>>(fused1 + 512, 2048, W3T, b3, fused3, 4096, 8192, 4096, 512);

  // fused rope + attention (output over q cols of fused2)
  attn_rope<<<8192, 256, 0, stream>>>(fused1, fused2, fused3);

  // output projection -> fp32 d_out                  M=8192 N=2048 K=2048
  gemm_bt256<float><<<dim3(8, 32), 512, 0, stream>>>(fused2, 3072, WoT, bo, (float*)d_out, 2048, 8192, 2048, 2048);
}

// Round 5
// 450.271 us; speedup vs baseline: 1.2253x; 1.0711x over previous
//
#include <hip/hip_runtime.h>
#include <hip/hip_bf16.h>
#include <stdint.h>

// MLA fused pipeline, fp32 I/O, bf16 MFMA internals.
// R11: de-lockstep the 8-phase loop. R10 counters: FETCH 135->54MB (T1 swizzle
// confirmed), dur 100->86us, but MfmaUtil only 32% with HBM 18% and VALU 12%
// -> schedule-bound. 16 barriers/iter kept both waves/SIMD in lockstep: both
// drain LDS simultaneously, both MFMA simultaneously -> pipe idles every
// drain. This version keeps barriers ONLY at the vmcnt gates (4/iter, every
// 2 phases) - the only true rendezvous (per-wave vmcnt can't see other waves'
// staged loads). No in-loop lgkmcnt (compiler emits fine-grained waits, m97).
// Waves now slip into anti-phase: one wave's MFMA covers the other's drain;
// setprio(1) around MFMA finally has role diversity to arbitrate (T5).
// Hazard ledger (re-verified): stages target regions >=5 phases ahead of any
// reader; within a 2-phase span no region is both read and re-staged; a
// wave's reads complete before its MFMAs (compiler lgkm) which precede the
// gate barrier; gates vmcnt(8) at p2/p4/p6/p8 retire exactly the half-tiles
// the next span reads. Compiler fences ("" memory) pin reads above stages
// and below gate barriers. Same per-acc K order -> bit-identical results.
// Keeps from R10: st_16x32 swizzle (conflicts==0), T1 XCD-chunked block
// swizzle, zero per-phase address VALU, bounded OOB tail prefetch (<=448B,
// all call sites inside ws/d_out), bf16 LDS-repack epilogue.

typedef __bf16 bf16_t;
typedef __bf16 bf16x8 __attribute__((ext_vector_type(8)));
typedef float f32x4 __attribute__((ext_vector_type(4)));

__device__ __forceinline__ void async_copy16(const void* g, void* l) {
  __builtin_amdgcn_global_load_lds(
      (__attribute__((address_space(1))) void*)(void*)g,
      (__attribute__((address_space(3))) void*)l, 16, 0, 0);
}

// ---------------------------------------------------------------------------
// GEMM: C[M,N](ldc) = A[M,K](lda) @ BT[N,K]^T + bias. bf16 in, OT out.
// 256x256 tile, BK=64 dbuf, 512 threads (8 waves 2Mx4N, 128x64 each).
// M%256==0, N%256==0, K%128==0. A and BT must be readable 448B past end
// (tail prefetch; never consumed). grid.x*grid.y % 8 == 0.
// ---------------------------------------------------------------------------
template <typename OT>
__global__ __launch_bounds__(512, 2) void gemm_bt256(
    const bf16_t* __restrict__ A, long lda,
    const bf16_t* __restrict__ BT,
    const float* __restrict__ bias,
    OT* __restrict__ C, long ldc,
    int M, int N, int K)
{
  __shared__ __align__(16) bf16_t As[2][16384];   // [buf][32 subtiles x 512]
  __shared__ __align__(16) bf16_t Bs[2][16384];

  const int tid  = threadIdx.x;
  const int lane = tid & 63;
  const int w    = tid >> 6;
  const int wm   = w >> 2, wn = w & 3;            // wave grid 2 x 4
  const int quad = lane >> 4, r16 = lane & 15;

  // T1: XCD-chunked swizzle (bijective since nwg % 8 == 0 for all grids).
  const int nwg = gridDim.x * gridDim.y;
  int wg = blockIdx.y * gridDim.x + blockIdx.x;
  wg = (wg & 7) * (nwg >> 3) + (wg >> 3);
  const int bx = wg % gridDim.x, by = wg / gridDim.x;
  const long row0 = (long)by * 256;
  const long col0 = (long)bx * 256;

  const bf16_t* Ab = A + row0 * lda;
  const bf16_t* Bb = BT + col0 * (long)K;

  // ds_read element offset (st_16x32 swizzle): logical (r=R*16+r16,
  // k=Kc*32+quad*8..) -> elem (R*2+Kc)*512 + r16*32 + (quad*8 ^ (r16&8?16:0))
  const int rdoff = r16 * 32 + ((quad * 8) ^ ((r16 & 8) ? 16 : 0));

  // staging: one global_load_lds fills one 1024B subtile linearly; lane l
  // holds (row l>>2, 16B chunk l&3); inverse swizzle on the global source.
  const int srin = lane >> 2;
  const int sksw = ((lane & 3) * 8) ^ ((lane & 32) ? 16 : 0);

  // Running per-wave global pointers: subtile-half s=0 (rows w*16..) and
  // s=1 (rows (8+w)*16..). Advanced += 128 elems (2 K-tiles) per iteration.
  const bf16_t* pA0 = Ab + (long)(w * 16 + srin) * lda + sksw;
  const bf16_t* pA1 = Ab + (long)((8 + w) * 16 + srin) * lda + sksw;
  const bf16_t* pB0 = Bb + (long)(w * 16 + srin) * K + sksw;
  const bf16_t* pB1 = Bb + (long)((8 + w) * 16 + srin) * K + sksw;

  f32x4 acc[8][4];
#pragma unroll
  for (int i = 0; i < 8; i++)
#pragma unroll
    for (int j = 0; j < 4; j++)
      acc[i][j] = (f32x4){0.f, 0.f, 0.f, 0.f};

  bf16x8 av[4], bv[4];

  // stage one operand-half: koff/Kc compile-time -> ptr+literal addresses.
#define STA(koff, dbuf, Kc)                                                  \
  async_copy16(pA0 + (koff) + (Kc) * 32, &As[dbuf][(w * 2 + (Kc)) << 9]);    \
  async_copy16(pA1 + (koff) + (Kc) * 32, &As[dbuf][((8 + w) * 2 + (Kc)) << 9])
#define STB(koff, dbuf, Kc)                                                  \
  async_copy16(pB0 + (koff) + (Kc) * 32, &Bs[dbuf][(w * 2 + (Kc)) << 9]);    \
  async_copy16(pB1 + (koff) + (Kc) * 32, &Bs[dbuf][((8 + w) * 2 + (Kc)) << 9])

  // Phase: reads | fence | stage | setprio MFMA | [gate: vmcnt(8)+bar+fence]
  // No barrier/lgkmcnt on non-gate phases: waves free-run within each
  // 2-phase span (max skew 2 phases; stage lead is 5-6 phases -> safe).
#define PHASE(RBUF, KH, MH, LOADB, STAGE_STMT, GATE)                         \
  {                                                                          \
    _Pragma("unroll")                                                        \
    for (int i_ = 0; i_ < 4; i_++)                                           \
      av[i_] = *(const bf16x8*)(&As[RBUF][0] +                               \
                (((wm * 8 + (MH) * 4 + i_) * 2 + (KH)) << 9) + rdoff);       \
    if (LOADB) {                                                             \
      _Pragma("unroll")                                                      \
      for (int j_ = 0; j_ < 4; j_++)                                         \
        bv[j_] = *(const bf16x8*)(&Bs[RBUF][0] +                             \
                  (((wn * 4 + j_) * 2 + (KH)) << 9) + rdoff);                \
    }                                                                        \
    asm volatile("" ::: "memory");                                           \
    STAGE_STMT;                                                              \
    __builtin_amdgcn_s_setprio(1);                                           \
    _Pragma("unroll")                                                        \
    for (int i_ = 0; i_ < 4; i_++)                                           \
      _Pragma("unroll")                                                      \
      for (int j_ = 0; j_ < 4; j_++)                                         \
        acc[(MH) * 4 + i_][j_] = __builtin_amdgcn_mfma_f32_16x16x32_bf16(    \
            av[i_], bv[j_], acc[(MH) * 4 + i_][j_], 0, 0, 0);                \
    __builtin_amdgcn_s_setprio(0);                                           \
    if (GATE) {                                                              \
      asm volatile("s_waitcnt vmcnt(8)" ::: "memory");                       \
      __builtin_amdgcn_s_barrier();                                          \
      asm volatile("" ::: "memory");                                         \
    }                                                                        \
  }

  // Prologue: E0 kh0, E0 kh1, O0 kh0 (6 stages = 12 loads), retire E0-kh0.
  STA(0, 0, 0);
  STB(0, 0, 0);
  STA(0, 0, 1);
  STB(0, 0, 1);
  STA(64, 1, 0);
  STB(64, 1, 0);
  asm volatile("s_waitcnt vmcnt(8)" ::: "memory");
  __builtin_amdgcn_s_barrier();
  asm volatile("" ::: "memory");

  const int NI = K >> 7;                          // 2 K-tiles per iteration
  for (int it = 0; it < NI; it++) {
    // tiles E (buf0) phases 1-4, O (buf1) phases 5-8; stage lead 5-6 phases.
    PHASE(0, 0, 0, true,  STA(64, 1, 1),  false)  // p1: stage A-O-kh1
    PHASE(0, 0, 1, false, STB(64, 1, 1),  true)   // p2: B-O-kh1; gate
    PHASE(0, 1, 0, true,  STA(128, 0, 0), false)  // p3: A-T2-kh0
    PHASE(0, 1, 1, false, STB(128, 0, 0), true)   // p4: gate
    PHASE(1, 0, 0, true,  STA(128, 0, 1), false)  // p5: A-T2-kh1
    PHASE(1, 0, 1, false, STB(128, 0, 1), true)   // p6: gate
    PHASE(1, 1, 0, true,  STA(192, 1, 0), false)  // p7: A-T3-kh0
    PHASE(1, 1, 1, false, STB(192, 1, 0), true)   // p8: gate
    pA0 += 128; pA1 += 128; pB0 += 128; pB1 += 128;
  }
#undef PHASE
#undef STA
#undef STB

  // Drain remaining staged (tail garbage) loads before LDS reuse / exit.
  asm volatile("s_waitcnt vmcnt(0)" ::: "memory");
  __builtin_amdgcn_s_barrier();
  asm volatile("" ::: "memory");

  // Bias into acc (C/D layout: col=lane&15, row=quad*4+reg, m89-verified).
#pragma unroll
  for (int j = 0; j < 4; j++) {
    const float bj = bias[col0 + wn * 64 + j * 16 + r16];
#pragma unroll
    for (int i = 0; i < 8; i++) {
      acc[i][j][0] += bj; acc[i][j][1] += bj;
      acc[i][j][2] += bj; acc[i][j][3] += bj;
    }
  }

  if constexpr (sizeof(OT) == 2) {
    // Repack epilogue through LDS: 8 wave regions [128][64] -> 512B rows.
    bf16_t* wreg = (w < 4) ? &As[w >> 1][(w & 1) * 8192]
                           : &Bs[(w - 4) >> 1][((w - 4) & 1) * 8192];
#pragma unroll
    for (int i = 0; i < 8; i++)
#pragma unroll
      for (int j = 0; j < 4; j++)
#pragma unroll
        for (int r = 0; r < 4; r++)
          wreg[(i * 16 + quad * 4 + r) * 64 + j * 16 + r16] = (bf16_t)acc[i][j][r];
    __syncthreads();
#pragma unroll
    for (int itr = 0; itr < 16; itr++) {
      const int r = itr * 16 + (tid >> 5);
      const int c = (tid & 31) * 8;
      const int ww = ((r >> 7) << 2) + (c >> 6);
      const bf16_t* src = ((ww < 4) ? &As[ww >> 1][(ww & 1) * 8192]
                                    : &Bs[(ww - 4) >> 1][((ww - 4) & 1) * 8192])
                          + (r & 127) * 64 + (c & 63);
      *(bf16x8*)((bf16_t*)C + (row0 + r) * ldc + col0 + c) = *(const bf16x8*)src;
    }
  } else {
    // fp32 output: 16-lane x 4B = 64B segments, no amplification; direct.
#pragma unroll
    for (int j = 0; j < 4; j++) {
      const long col = col0 + wn * 64 + j * 16 + r16;
#pragma unroll
      for (int i = 0; i < 8; i++) {
        const long row = row0 + wm * 128 + i * 16 + quad * 4;
#pragma unroll
        for (int r = 0; r < 4; r++)
          C[(row + r) * ldc + col] = (OT)acc[i][j][r];
      }
    }
  }
}

// ---------------------------------------------------------------------------
// Weight transpose+convert: in fp32 [R][C] -> out bf16 [C][R]. 32x32 tiles,
// block (32,8). out may point into a stacked [N_tot,K] buffer.
// ---------------------------------------------------------------------------
__global__ void transpose_f32_bf16(const float* __restrict__ in, bf16_t* __restrict__ out,
                                   int R, int C)
{
  __shared__ bf16_t tile[32][33];
  const int cb = blockIdx.x * 32, rb = blockIdx.y * 32;
  const int tx = threadIdx.x, ty = threadIdx.y;
#pragma unroll
  for (int i = 0; i < 32; i += 8)
    tile[ty + i][tx] = (bf16_t)in[(size_t)(rb + ty + i) * C + cb + tx];
  __syncthreads();
#pragma unroll
  for (int i = 0; i < 32; i += 8)
    out[(size_t)(cb + ty + i) * R + rb + tx] = tile[tx][ty + i];
}

// ---------------------------------------------------------------------------
// fp32 -> bf16 elementwise convert, 8 elems/thread. n % 8 == 0.
// ---------------------------------------------------------------------------
__global__ void cvt_f32_bf16(const float* __restrict__ in, bf16_t* __restrict__ out, long n)
{
  const long i = ((long)blockIdx.x * blockDim.x + threadIdx.x) * 8;
  if (i >= n) return;
  const float4 a = *(const float4*)(in + i);
  const float4 b = *(const float4*)(in + i + 4);
  bf16x8 o;
  o[0] = (bf16_t)a.x; o[1] = (bf16_t)a.y; o[2] = (bf16_t)a.z; o[3] = (bf16_t)a.w;
  o[4] = (bf16_t)b.x; o[5] = (bf16_t)b.y; o[6] = (bf16_t)b.z; o[7] = (bf16_t)b.w;
  *(bf16x8*)(out + i) = o;
}

// ---------------------------------------------------------------------------
// Concatenate biases for the merged GEMMs. 9216 threads.
// b1[2048]={bc,bckv,bkr} b2[3072]={bcq,bqr} b3[4096]={bck,bv}
// ---------------------------------------------------------------------------
__global__ void concat_bias(const float* bc, const float* bckv, const float* bkr,
                            const float* bcq, const float* bqr,
                            const float* bck, const float* bv,
                            float* b1, float* b2, float* b3)
{
  const int t = blockIdx.x * 256 + threadIdx.x;
  if (t < 2048) {
    b1[t] = (t < 512) ? bc[t] : (t < 1024) ? bckv[t - 512] : bkr[t - 1024];
  } else if (t < 5120) {
    const int u = t - 2048;
    b2[u] = (u < 2048) ? bcq[u] : bqr[u - 2048];
  } else if (t < 9216) {
    const int u = t - 5120;
    b3[u] = (u < 2048) ? bck[u] : bv[u - 2048];
  }
}

// ---------------------------------------------------------------------------
// Fused RoPE + per-token 16x16 head attention over the fused buffers.
// fused1[8192][2048]: cols 1024.. = kr(pre-rope)
// fused2[8192][3072]: cols 0..2047 = q (overwritten with output), 2048.. = qr
// fused3[8192][4096]: cols 0..2047 = k, 2048.. = v
// ---------------------------------------------------------------------------
__global__ __launch_bounds__(256) void attn_rope(
    const bf16_t* __restrict__ f1, bf16_t* f2, const bf16_t* __restrict__ f3)
{
  const int tok = blockIdx.x;
  const int pos = tok & 4095;   // position within sequence (S=4096)
  const int tid = threadIdx.x;

  __shared__ __align__(16) float qf[16 * 204];
  __shared__ __align__(16) float kf[16 * 204];
  __shared__ __align__(16) float vf[16 * 132];
  __shared__ float sc[256];

  const bf16_t* q  = f2 + (size_t)tok * 3072;
  const bf16_t* qr = q + 2048;
  const bf16_t* k  = f3 + (size_t)tok * 4096;
  const bf16_t* v  = k + 2048;
  const bf16_t* kr = f1 + (size_t)tok * 2048 + 1024;

  {
    const int h = tid >> 4, d = (tid & 15) * 8;
    bf16x8 xq = *(const bf16x8*)(q + tid * 8);
    bf16x8 xk = *(const bf16x8*)(k + tid * 8);
    bf16x8 xv = *(const bf16x8*)(v + tid * 8);
    float* qd = qf + h * 204 + d;
    float* kd = kf + h * 204 + d;
    float* vd = vf + h * 132 + d;
#pragma unroll
    for (int e = 0; e < 8; e++) {
      qd[e] = (float)xq[e];
      kd[e] = (float)xk[e];
      vd[e] = (float)xv[e];
    }
  }

  // RoPE: inv_freq[j] = 10000^(-j/32) = 2^(-j*log2(10000)/32)
  for (int p = tid; p < 512; p += 256) {
    const int h = p >> 5, j = p & 31;
    const float x1 = (float)qr[h * 64 + j];
    const float x2 = (float)qr[h * 64 + j + 32];
    const float y1 = (float)kr[h * 64 + j];
    const float y2 = (float)kr[h * 64 + j + 32];
    const float ang = (float)pos * exp2f((float)j * -0.41524101186092029f);
    float sn, cs;
    sincosf(ang, &sn, &cs);
    qf[h * 204 + 128 + j] = x1 * cs - x2 * sn;
    qf[h * 204 + 160 + j] = x2 * cs + x1 * sn;
    kf[h * 204 + 128 + j] = y1 * cs - y2 * sn;
    kf[h * 204 + 160 + j] = y2 * cs + y1 * sn;
  }
  __syncthreads();

  {
    const int i = tid >> 4, j = tid & 15;
    const float4* qrow = (const float4*)(qf + i * 204);
    const float4* krow = (const float4*)(kf + j * 204);
    float d0 = 0.f, d1 = 0.f, d2 = 0.f, d3 = 0.f;
#pragma unroll 8
    for (int dd = 0; dd < 48; dd++) {
      const float4 a = qrow[dd], b = krow[dd];
      d0 = fmaf(a.x, b.x, d0);
      d1 = fmaf(a.y, b.y, d1);
      d2 = fmaf(a.z, b.z, d2);
      d3 = fmaf(a.w, b.w, d3);
    }
    const float s = (d0 + d1 + d2 + d3) * 0.07216878364870323f; // 1/sqrt(192)
    float m = s;
    m = fmaxf(m, __shfl_xor(m, 1));
    m = fmaxf(m, __shfl_xor(m, 2));
    m = fmaxf(m, __shfl_xor(m, 4));
    m = fmaxf(m, __shfl_xor(m, 8));
    const float e = __expf(s - m);
    float sum = e;
    sum += __shfl_xor(sum, 1);
    sum += __shfl_xor(sum, 2);
    sum += __shfl_xor(sum, 4);
    sum += __shfl_xor(sum, 8);
    sc[i * 16 + j] = e / sum;
  }
  __syncthreads();

  {
    const int i = tid >> 4, dp = (tid & 15) * 8;
    float4 a0 = {0.f, 0.f, 0.f, 0.f}, a1 = {0.f, 0.f, 0.f, 0.f};
#pragma unroll
    for (int j = 0; j < 16; j++) {
      const float a = sc[i * 16 + j];
      const float4* vrow = (const float4*)(vf + j * 132 + dp);
      const float4 v0 = vrow[0], v1 = vrow[1];
      a0.x = fmaf(a, v0.x, a0.x);
      a0.y = fmaf(a, v0.y, a0.y);
      a0.z = fmaf(a, v0.z, a0.z);
      a0.w = fmaf(a, v0.w, a0.w);
      a1.x = fmaf(a, v1.x, a1.x);
      a1.y = fmaf(a, v1.y, a1.y);
      a1.z = fmaf(a, v1.z, a1.z);
      a1.w = fmaf(a, v1.w, a1.w);
    }
    bf16x8 o;
    o[0] = (bf16_t)a0.x; o[1] = (bf16_t)a0.y; o[2] = (bf16_t)a0.z; o[3] = (bf16_t)a0.w;
    o[4] = (bf16_t)a1.x; o[5] = (bf16_t)a1.y; o[6] = (bf16_t)a1.z; o[7] = (bf16_t)a1.w;
    // write over q columns of fused2 (this block read its own q above)
    *(bf16x8*)(f2 + (size_t)tok * 3072 + i * 128 + dp) = o;
  }
}

// ---------------------------------------------------------------------------
extern "C" void kernel_launch(void* const* d_in, const int* in_sizes, int n_in,
                              void* d_out, int out_size, void* d_ws, size_t ws_size,
                              hipStream_t stream)
{
  (void)in_sizes; (void)n_in; (void)out_size; (void)ws_size;

  const float* h_t  = (const float*)d_in[0];
  const float* Wc   = (const float*)d_in[1];
  const float* bc   = (const float*)d_in[2];
  const float* Wcq  = (const float*)d_in[3];
  const float* bcq  = (const float*)d_in[4];
  const float* Wqr  = (const float*)d_in[5];
  const float* bqr  = (const float*)d_in[6];
  const float* Wckv = (const float*)d_in[7];
  const float* bckv = (const float*)d_in[8];
  const float* Wck  = (const float*)d_in[9];
  const float* bck  = (const float*)d_in[10];
  const float* Wkr  = (const float*)d_in[11];
  const float* bkr  = (const float*)d_in[12];
  const float* Wv   = (const float*)d_in[13];
  const float* bv   = (const float*)d_in[14];
  const float* Wo   = (const float*)d_in[15];
  const float* bo   = (const float*)d_in[16];

  bf16_t* ws = (bf16_t*)d_ws;
  // ws layout (bf16 elems) — total 87,556,096 = 175,112,192 B (proven fit R4)
  bf16_t* W1T    = ws + 0;         // [2048,2048] rows: WcT 0-511, WckvT 512-1023, WkrT 1024-2047
  bf16_t* W2T    = ws + 4194304;   // [3072,512]  rows: WcqT 0-2047, WqrT 2048-3071
  bf16_t* W3T    = ws + 5767168;   // [4096,512]  rows: WckT 0-2047, WvT 2048-4095
  bf16_t* WoT    = ws + 7864320;   // [2048,2048]
  bf16_t* fused1 = ws + 12058624;  // [8192,2048] cq|ckv|kr_pre
  bf16_t* fused2 = ws + 28835840;  // [8192,3072] q|qr  (q cols become attn out)
  bf16_t* fused3 = ws + 54001664;  // [8192,4096] k|v

  // d_out as scratch until the final GEMM: bf16 h_t copy + concat'd biases
  bf16_t* hbf = (bf16_t*)d_out;                          // 16,777,216 elems (33.5 MB)
  float*  b1  = (float*)((char*)d_out + 33554432);       // 2048 f
  float*  b2  = b1 + 2048;                               // 3072 f
  float*  b3  = b2 + 3072;                               // 4096 f

  const dim3 tb(32, 8);
  transpose_f32_bf16<<<dim3(16, 64), tb, 0, stream>>>(Wc,   W1T,                2048, 512);
  transpose_f32_bf16<<<dim3(16, 64), tb, 0, stream>>>(Wckv, W1T + 512  * 2048,  2048, 512);
  transpose_f32_bf16<<<dim3(32, 64), tb, 0, stream>>>(Wkr,  W1T + 1024 * 2048,  2048, 1024);
  transpose_f32_bf16<<<dim3(64, 16), tb, 0, stream>>>(Wcq,  W2T,                512, 2048);
  transpose_f32_bf16<<<dim3(32, 16), tb, 0, stream>>>(Wqr,  W2T + 2048 * 512,   512, 1024);
  transpose_f32_bf16<<<dim3(64, 16), tb, 0, stream>>>(Wck,  W3T,                512, 2048);
  transpose_f32_bf16<<<dim3(64, 16), tb, 0, stream>>>(Wv,   W3T + 2048 * 512,   512, 2048);
  transpose_f32_bf16<<<dim3(64, 64), tb, 0, stream>>>(Wo,   WoT,                2048, 2048);
  concat_bias<<<36, 256, 0, stream>>>(bc, bckv, bkr, bcq, bqr, bck, bv, b1, b2, b3);
  cvt_f32_bf16<<<8192, 256, 0, stream>>>(h_t, hbf, 16777216L);

  // stage 1: [cq|ckv|kr_pre] = hbf @ [Wc|Wckv|Wkr]   M=8192 N=2048 K=2048
  gemm_bt256<bf16_t><<<dim3(8, 32), 512, 0, stream>>>(hbf, 2048, W1T, b1, fused1, 2048, 8192, 2048, 2048);
  // stage 2a: [q|qr] = cq @ [Wcq|Wqr]                M=8192 N=3072 K=512
  gemm_bt256<bf16_t><<<dim3(12, 32), 512, 0, stream>>>(fused1, 2048, W2T, b2, fused2, 3072, 8192, 3072, 512);
  // stage 2b: [k|v] = ckv @ [Wck|Wv]                 M=8192 N=4096 K=512
  gemm_bt256<bf16_t><<<dim3(16, 32), 512, 0, stream>>>(fused1 + 512, 2048, W3T, b3, fused3, 4096, 8192, 4096, 512);

  // fused rope + attention (output over q cols of fused2)
  attn_rope<<<8192, 256, 0, stream>>>(fused1, fused2, fused3);

  // output projection -> fp32 d_out                  M=8192 N=2048 K=2048
  gemm_bt256<float><<<dim3(8, 32), 512, 0, stream>>>(fused2, 3072, WoT, bo, (float*)d_out, 2048, 8192, 2048, 2048);
}